// Round 2
// baseline (1790.400 us; speedup 1.0000x reference)
//
#include <hip/hip_runtime.h>

// SE(3)-Transformer backbone, fp32, MI355X.
// Dims: B=16 N=64 FIN=16 C=32 D=4 (mg: l0=1, l1=3, l2=5, l3=7 -> 16) L=4 H=8 hd=4
// f layout: [b*64+n][c][mg] flat, 512 floats per node.
// nodefeats layout per node (1792 floats):
//   +0    sc_k[l*32+c]  (128)
//   +128  sc_v[l*32+c]  (128)
//   +256  id_k[c*16+mg] (512)
//   +768  id_v[c*16+mg] (512)
//   +1280 q   [c*16+mg] (512)

__device__ __forceinline__ int lof(int mg)   { return (mg==0)?0:((mg<4)?1:((mg<9)?2:3)); }
__device__ __forceinline__ int mgb_of(int l) { return (l==0)?0:((l==1)?1:((l==2)?4:9)); }

// ---------------- embed: f0 = h @ Wemb, higher degrees zero ----------------
__global__ __launch_bounds__(256) void embed_k(const float* __restrict__ h,
                                               const float* __restrict__ Wemb,
                                               float* __restrict__ f) {
  int idx = blockIdx.x * 256 + threadIdx.x;   // covers 16*64*512 = 524288
  int node = idx >> 9;
  int rem  = idx & 511;
  int c = rem >> 4, mg = rem & 15;
  float v = 0.f;
  if (mg == 0) {
    const float* hh = h + node * 16;
    #pragma unroll
    for (int i = 0; i < 16; i++) v += hh[i] * Wemb[i * 32 + c];
  }
  f[idx] = v;
}

// ---------------- per-node K/V/Q projections ----------------
__global__ __launch_bounds__(256) void nodefeats_k(const float* __restrict__ f,
    const float* __restrict__ Wk, const float* __restrict__ Wv,
    const float* __restrict__ Wq, float* __restrict__ nf, int li) {
  __shared__ __align__(16) float fl[512];
  const int node = blockIdx.x;
  const int tid = threadIdx.x;
  reinterpret_cast<float2*>(fl)[tid] =
      reinterpret_cast<const float2*>(f + (size_t)node * 512)[tid];
  __syncthreads();
  float* out = nf + (size_t)node * 1792;
  #pragma unroll
  for (int k = 0; k < 7; k++) {
    int o = tid + k * 256;
    float acc = 0.f;
    if (o < 128) {                       // sc_k
      int l = o >> 5, c = o & 31;
      const float* w = Wk + (size_t)(((li*4 + l)*2 + 0)*32 + c) * 32;
      #pragma unroll
      for (int i = 0; i < 32; i++) acc += w[i] * fl[i*16];
    } else if (o < 256) {                // sc_v
      int o2 = o - 128; int l = o2 >> 5, c = o2 & 31;
      const float* w = Wv + (size_t)(((li*4 + l)*2 + 0)*32 + c) * 32;
      #pragma unroll
      for (int i = 0; i < 32; i++) acc += w[i] * fl[i*16];
    } else if (o < 768) {                // id_k
      int o2 = o - 256; int c = o2 >> 4, mg = o2 & 15, l = lof(mg);
      const float* w = Wk + (size_t)(((li*4 + l)*2 + 1)*32 + c) * 32;
      #pragma unroll
      for (int i = 0; i < 32; i++) acc += w[i] * fl[i*16 + mg];
    } else if (o < 1280) {               // id_v
      int o2 = o - 768; int c = o2 >> 4, mg = o2 & 15, l = lof(mg);
      const float* w = Wv + (size_t)(((li*4 + l)*2 + 1)*32 + c) * 32;
      #pragma unroll
      for (int i = 0; i < 32; i++) acc += w[i] * fl[i*16 + mg];
    } else {                             // q
      int o2 = o - 1280; int c = o2 >> 4, mg = o2 & 15, l = lof(mg);
      const float* w = Wq + (size_t)((li*4 + l)*32 + c) * 32;
      #pragma unroll
      for (int i = 0; i < 32; i++) acc += w[i] * fl[i*16 + mg];
    }
    out[o] = acc;
  }
}

// ---------------- fused attention layer: one block per (b, dst) ----------------
__global__ __launch_bounds__(256, 4) void attn_k(
    const float* __restrict__ f, const float* __restrict__ nf,
    float* __restrict__ fnext,
    const float* __restrict__ x, const int* __restrict__ bond,
    const float* __restrict__ rw1, const float* __restrict__ rb1,
    const float* __restrict__ rw2, const float* __restrict__ rb2,
    const float* __restrict__ Wself, const float* __restrict__ gnorm,
    const float* __restrict__ bnorm, int li) {
  __shared__ __align__(16) float Ysh[64][16];     // Y per source; reused as o_lds in epilogue
  __shared__ float rinsh[64][8];                  // dist + 4 bond one-hots
  __shared__ float qsh[32 * 17];                  // q, padded stride 17
  __shared__ __align__(16) float fdst[512];       // dst fiber (Wself skip)
  __shared__ __align__(16) float hmidAll[64][32]; // radial hidden, ALL edges; reused as fac in epilogue
  __shared__ __align__(16) float logitsp[2][4][8][4]; // [buf][e][h][lw] partial logits
  __shared__ __align__(8)  float r23g[2][4][320]; // [buf][e][c*10 + l*2 + p] v-path r

  const int tid = threadIdx.x;
  const int bx  = blockIdx.x;
  const int b = bx >> 6, d = bx & 63;
  const int o0 = 2 * tid;
  const int lw = tid >> 6;              // wave id == degree l of this thread's r-columns
  const int jj = (tid >> 4) & 3;        // radial path 0..3
  const int c0 = o0 & 31;               // even channel of the r-column pair
  const int hH = c0 >> 2;
  const int mgb = mgb_of(lw);
  const int Ml = 2 * lw + 1;

  // ---- block-start loads ----
  {
    const float2 qv = *reinterpret_cast<const float2*>(nf + (size_t)bx * 1792 + 1280 + o0);
    int qc = tid >> 3, qm = 2 * (tid & 7);
    qsh[qc * 17 + qm] = qv.x;
    qsh[qc * 17 + qm + 1] = qv.y;
    *reinterpret_cast<float2*>(fdst + o0) =
        *reinterpret_cast<const float2*>(f + (size_t)bx * 512 + o0);
  }
  if (tid < 64) {               // inline geometry for source s = tid
    const int s = tid;
    const float* xb = x + (size_t)b * 192;
    float xd = xb[d*3+0], yd = xb[d*3+1], zd = xb[d*3+2];
    float dx = xb[s*3+0] - xd, dy = xb[s*3+1] - yd, dz = xb[s*3+2] - zd;
    float dist = sqrtf(dx*dx + dy*dy + dz*dz + 1e-6f);
    float inv = 1.0f / dist;
    float xx = dx*inv, yy = dy*inv, zz = dz*inv;
    float* Y = Ysh[s];
    Y[0]  = 0.28209479177387814f;
    Y[1]  = 0.4886025119029199f * yy;
    Y[2]  = 0.4886025119029199f * zz;
    Y[3]  = 0.4886025119029199f * xx;
    Y[4]  = 1.0925484305920792f * xx * yy;
    Y[5]  = 1.0925484305920792f * yy * zz;
    Y[6]  = 0.31539156525252005f * (3.0f*zz*zz - 1.0f);
    Y[7]  = 1.0925484305920792f * xx * zz;
    Y[8]  = 0.5462742152960396f * (xx*xx - yy*yy);
    Y[9]  = 0.5900435899266435f * yy * (3.0f*xx*xx - yy*yy);
    Y[10] = 2.890611442640554f  * xx * yy * zz;
    Y[11] = 0.4570457994644658f * yy * (5.0f*zz*zz - 1.0f);
    Y[12] = 0.3731763325901154f * zz * (5.0f*zz*zz - 3.0f);
    Y[13] = 0.4570457994644658f * xx * (5.0f*zz*zz - 1.0f);
    Y[14] = 1.445305721320277f  * zz * (xx*xx - yy*yy);
    Y[15] = 0.5900435899266435f * xx * (xx*xx - yy*yy);
    rinsh[s][0] = dist;
    int bt = bond[(size_t)b * 4096 + d * 64 + s];
    bt = bt < 0 ? 0 : (bt > 4 ? 4 : bt);
    rinsh[s][1] = (bt == 1) ? 1.f : 0.f;
    rinsh[s][2] = (bt == 2) ? 1.f : 0.f;
    rinsh[s][3] = (bt == 3) ? 1.f : 0.f;
    rinsh[s][4] = (bt == 4) ? 1.f : 0.f;
  }

  // rw2 columns for this thread's 2 outputs, resident in registers
  float2 w2[32];
  #pragma unroll
  for (int i = 0; i < 32; i++)
    w2[i] = *reinterpret_cast<const float2*>(rw2 + ((size_t)li*32 + i) * 512 + o0);
  const float2 rbv = *reinterpret_cast<const float2*>(rb2 + li * 512 + o0);

  const int ch = tid & 31;              // radial-hidden channel for precompute
  float w1r[5];
  #pragma unroll
  for (int i = 0; i < 5; i++) w1r[i] = rw1[(li*5 + i)*32 + ch];
  const float b1r = rb1[li*32 + ch];

  // o-accumulator slot decode (flat = c*16+mg, slots o0, o0+1)
  const int oc = tid >> 3;
  const int mg0 = 2 * (tid & 7), mg1 = mg0 + 1;
  const int l0 = lof(mg0), l1 = lof(mg1);
  const int ohh = oc >> 2;

  float m_run = -1e30f, l_run = 0.0f;
  float acc0 = 0.0f, acc1 = 0.0f;

  __syncthreads();

  // ---- radial hidden (LN+relu) for ALL 64 edges, all lanes active ----
  #pragma unroll
  for (int p = 0; p < 8; p++) {
    const int e = p * 8 + (tid >> 5);
    float pre = b1r;
    #pragma unroll
    for (int i = 0; i < 5; i++) pre += rinsh[e][i] * w1r[i];
    float mu = pre;
    #pragma unroll
    for (int k = 16; k >= 1; k >>= 1) mu += __shfl_xor(mu, k, 32);
    mu *= 0.03125f;
    float dv = pre - mu;
    float var = dv * dv;
    #pragma unroll
    for (int k = 16; k >= 1; k >>= 1) var += __shfl_xor(var, k, 32);
    var *= 0.03125f;
    hmidAll[e][ch] = fmaxf(dv * rsqrtf(var + 1e-6f), 0.0f);
  }
  __syncthreads();

  for (int g = 0; g < 16; g++) {
    const int sb = g * 4;
    const int buf = g & 1;

    // prefetch id_v operands for step D (latency hides under projection FMAs)
    float2 riv[4];
    #pragma unroll
    for (int e = 0; e < 4; e++)
      riv[e] = *reinterpret_cast<const float2*>(
          nf + (size_t)(b*64 + sb + e)*1792 + 768 + o0);

    // B: r = hmid @ rw2 + rb2 for 4 edges, this thread's 2 columns
    float2 racc[4];
    #pragma unroll
    for (int e = 0; e < 4; e++) racc[e] = rbv;
    #pragma unroll
    for (int e = 0; e < 4; e++) {
      const float4* hp = reinterpret_cast<const float4*>(&hmidAll[sb + e][0]);
      float rx = racc[e].x, ry = racc[e].y;
      #pragma unroll
      for (int i4 = 0; i4 < 8; i4++) {
        float4 h4 = hp[i4];
        float2 wa = w2[i4*4+0], wb = w2[i4*4+1], wc = w2[i4*4+2], wd = w2[i4*4+3];
        rx += h4.x*wa.x + h4.y*wb.x + h4.z*wc.x + h4.w*wd.x;
        ry += h4.x*wa.y + h4.y*wb.y + h4.z*wc.y + h4.w*wd.y;
      }
      racc[e].x = rx; racc[e].y = ry;
    }

    // C: logits partials via shuffle-combine (jj 0,1) / stage v-path r (jj 2,3)
    if (jj <= 1) {
      #pragma unroll
      for (int e = 0; e < 4; e++) {
        const int s = sb + e;
        float pl;
        if (jj == 0) {
          const float2 sck = *reinterpret_cast<const float2*>(
              nf + (size_t)(b*64 + s)*1792 + lw*32 + c0);
          float qy0 = 0.f, qy1 = 0.f;
          for (int m = 0; m < Ml; m++) {
            const float Yv = Ysh[s][mgb + m];
            qy0 += qsh[c0*17 + mgb + m] * Yv;
            qy1 += qsh[(c0+1)*17 + mgb + m] * Yv;
          }
          pl = racc[e].x*sck.x*qy0 + racc[e].y*sck.y*qy1;
        } else {
          const float* idk = nf + (size_t)(b*64 + s)*1792 + 256;
          float a0 = 0.f, a1 = 0.f;
          for (int m = 0; m < Ml; m++) {
            a0 += idk[c0*16 + mgb + m]     * qsh[c0*17 + mgb + m];
            a1 += idk[(c0+1)*16 + mgb + m] * qsh[(c0+1)*17 + mgb + m];
          }
          pl = racc[e].x*a0 + racc[e].y*a1;
        }
        pl += __shfl_xor(pl, 16, 64);   // combine k-scalar + k-identity paths
        pl += __shfl_xor(pl, 1, 64);    // combine the 2 channel-pairs of a head
        if (jj == 0 && (tid & 1) == 0) logitsp[buf][e][hH][lw] = pl;
      }
    } else if (jj == 2) {
      #pragma unroll
      for (int e = 0; e < 4; e++) {
        const int s = sb + e;
        const float2 scv = *reinterpret_cast<const float2*>(
            nf + (size_t)(b*64 + s)*1792 + 128 + lw*32 + c0);
        r23g[buf][e][c0*10 + lw*2]     = racc[e].x * scv.x;
        r23g[buf][e][(c0+1)*10 + lw*2] = racc[e].y * scv.y;
      }
    } else {
      #pragma unroll
      for (int e = 0; e < 4; e++) {
        r23g[buf][e][c0*10 + lw*2 + 1]     = racc[e].x;
        r23g[buf][e][(c0+1)*10 + lw*2 + 1] = racc[e].y;
      }
    }
    __syncthreads();

    // D: online-softmax update of this thread's 2 o-slots
    {
      float lg[4];
      #pragma unroll
      for (int e = 0; e < 4; e++) {
        const int s = sb + e;
        const float4 lp = *reinterpret_cast<const float4*>(&logitsp[buf][e][ohh][0]);
        lg[e] = (s == d) ? -1e9f : (lp.x + lp.y + lp.z + lp.w) * 0.125f;
      }
      float m4 = fmaxf(fmaxf(lg[0], lg[1]), fmaxf(lg[2], lg[3]));
      float m_new = fmaxf(m_run, m4);
      float resc = __expf(m_run - m_new);
      acc0 *= resc; acc1 *= resc; l_run *= resc;
      #pragma unroll
      for (int e = 0; e < 4; e++) {
        const int s = sb + e;
        float w = __expf(lg[e] - m_new);
        l_run += w;
        const float2 ra = *reinterpret_cast<const float2*>(&r23g[buf][e][oc*10 + l0*2]);
        const float2 rb = *reinterpret_cast<const float2*>(&r23g[buf][e][oc*10 + l1*2]);
        acc0 += w * (ra.x * Ysh[s][mg0] + ra.y * riv[e].x);
        acc1 += w * (rb.x * Ysh[s][mg1] + rb.y * riv[e].y);
      }
      m_run = m_new;
    }
  }
  __syncthreads();   // protect Ysh before reuse as osh

  // ---- epilogue: normalize, Wself skip, NormSE3 gate, write ----
  const float invl = 1.0f / l_run;
  acc0 *= invl; acc1 *= invl;
  {
    const float* w0 = Wself + (size_t)((li*4 + l0)*32 + oc) * 32;
    const float* w1 = Wself + (size_t)((li*4 + l1)*32 + oc) * 32;
    #pragma unroll
    for (int i = 0; i < 32; i++) {
      acc0 += w0[i] * fdst[i*16 + mg0];
      acc1 += w1[i] * fdst[i*16 + mg1];
    }
  }
  float* osh = &Ysh[0][0];    // reuse
  osh[o0] = acc0; osh[o0 + 1] = acc1;
  __syncthreads();
  if (tid < 128) {
    const int c2 = tid >> 2, l2 = tid & 3;
    const int mb = mgb_of(l2), M2 = 2*l2 + 1;
    float ss = 0.f;
    for (int m = 0; m < M2; m++) { float v = osh[c2*16 + mb + m]; ss += v*v; }
    const float nrm = sqrtf(ss + 1e-6f);
    const float gg = gnorm[(li*4 + l2)*32 + c2];
    const float bb = bnorm[(li*4 + l2)*32 + c2];
    const float sg = fmaxf(gg*nrm + bb, 0.f);
    (&hmidAll[0][0])[c2*4 + l2] = sg / nrm;
  }
  __syncthreads();
  const float fac0 = (&hmidAll[0][0])[oc*4 + l0];
  const float fac1 = (&hmidAll[0][0])[oc*4 + l1];
  *reinterpret_cast<float2*>(fnext + (size_t)bx * 512 + o0) =
      make_float2(acc0 * fac0, acc1 * fac1);
}

// ---------------- readout: invariant norms -> mean over nodes -> Wfinal ----------------
__global__ __launch_bounds__(256) void readout_k(const float* __restrict__ f,
    const float* __restrict__ Wfinal, const float* __restrict__ bfinal,
    float* __restrict__ out) {
  __shared__ float invs[2][128];
  __shared__ float inv1[128];
  const int b = blockIdx.x;
  const int tid = threadIdx.x;
  const int j = tid & 127, half = tid >> 7;
  float p = 0.f;
  for (int n = half*32; n < half*32 + 32; n++) {
    const float* fn = f + (size_t)(b*64 + n) * 512;
    float v;
    if (j < 32) {
      v = fn[j*16];
    } else {
      int l = j >> 5, c = j & 31;
      int mb = mgb_of(l), M = 2*l + 1;
      float ss = 0.f;
      for (int m = 0; m < M; m++) { float t = fn[c*16 + mb + m]; ss += t*t; }
      v = sqrtf(ss + 1e-6f);
    }
    p += v;
  }
  invs[half][j] = p;
  __syncthreads();
  if (tid < 128) inv1[tid] = (invs[0][tid] + invs[1][tid]) * (1.0f / 64.0f);
  __syncthreads();
  if (tid < 128) {
    float acc = bfinal[tid];
    for (int k = 0; k < 128; k++) acc += inv1[k] * Wfinal[k*128 + tid];
    out[b*128 + tid] = acc;
  }
}

extern "C" void kernel_launch(void* const* d_in, const int* in_sizes, int n_in,
                              void* d_out, int out_size, void* d_ws, size_t ws_size,
                              hipStream_t stream) {
  (void)in_sizes; (void)n_in; (void)out_size; (void)ws_size;
  const float* h      = (const float*)d_in[0];
  const float* x      = (const float*)d_in[1];
  const int*   bond   = (const int*)d_in[2];
  const float* Wemb   = (const float*)d_in[3];
  const float* rw1    = (const float*)d_in[4];
  const float* rb1    = (const float*)d_in[5];
  const float* rw2    = (const float*)d_in[6];
  const float* rb2    = (const float*)d_in[7];
  const float* Wk     = (const float*)d_in[8];
  const float* Wv     = (const float*)d_in[9];
  const float* Wq     = (const float*)d_in[10];
  const float* Wself  = (const float*)d_in[11];
  const float* gnorm  = (const float*)d_in[12];
  const float* bnorm  = (const float*)d_in[13];
  const float* Wfinal = (const float*)d_in[14];
  const float* bfinal = (const float*)d_in[15];
  float* out = (float*)d_out;

  float* ws = (float*)d_ws;
  float* fA = ws;                       // 524288 floats
  float* fB = ws + 524288;              // 524288 floats
  float* nf = ws + 2 * 524288;          // 1024*1792 floats

  embed_k<<<2048, 256, 0, stream>>>(h, Wemb, fA);

  float* fc = fA; float* fn2 = fB;
  for (int li = 0; li < 4; li++) {
    nodefeats_k<<<1024, 256, 0, stream>>>(fc, Wk, Wv, Wq, nf, li);
    attn_k<<<1024, 256, 0, stream>>>(fc, nf, fn2, x, bond,
                                     rw1, rb1, rw2, rb2, Wself, gnorm, bnorm, li);
    float* t = fc; fc = fn2; fn2 = t;
  }

  readout_k<<<16, 256, 0, stream>>>(fc, Wfinal, bfinal, out);
}

// Round 3
// 1172.952 us; speedup vs baseline: 1.5264x; 1.5264x over previous
//
#include <hip/hip_runtime.h>

// SE(3)-Transformer backbone, fp32, MI355X.
// Dims: B=16 N=64 FIN=16 C=32 D=4 (mg: l0=1, l1=3, l2=5, l3=7 -> 16) L=4 H=8 hd=4
// f layout: [b*64+n][c][mg] flat, 512 floats per node.
// nodefeats layout per node (1792 floats):
//   +0    sc_k[l*32+c]  (128)
//   +128  sc_v[l*32+c]  (128)
//   +256  id_k[c*16+mg] (512)
//   +768  id_v[c*16+mg] (512)
//   +1280 q   [c*16+mg] (512)
//
// NOTE (round 2 lesson): do NOT add a min-waves arg to __launch_bounds__ here.
// (256,4) capped VGPR at 64 and spilled w2[32] (64 regs) to scratch ->
// ~1 GB/dispatch of global spill traffic, 1.6x slowdown.

__device__ __forceinline__ int lof(int mg)   { return (mg==0)?0:((mg<4)?1:((mg<9)?2:3)); }
__device__ __forceinline__ int mgb_of(int l) { return (l==0)?0:((l==1)?1:((l==2)?4:9)); }

// ---------------- embed: f0 = h @ Wemb, higher degrees zero ----------------
__global__ __launch_bounds__(256) void embed_k(const float* __restrict__ h,
                                               const float* __restrict__ Wemb,
                                               float* __restrict__ f) {
  int idx = blockIdx.x * 256 + threadIdx.x;   // covers 16*64*512 = 524288
  int node = idx >> 9;
  int rem  = idx & 511;
  int c = rem >> 4, mg = rem & 15;
  float v = 0.f;
  if (mg == 0) {
    const float* hh = h + node * 16;
    #pragma unroll
    for (int i = 0; i < 16; i++) v += hh[i] * Wemb[i * 32 + c];
  }
  f[idx] = v;
}

// ---------------- per-node K/V/Q projections ----------------
__global__ __launch_bounds__(256) void nodefeats_k(const float* __restrict__ f,
    const float* __restrict__ Wk, const float* __restrict__ Wv,
    const float* __restrict__ Wq, float* __restrict__ nf, int li) {
  __shared__ __align__(16) float fl[512];
  const int node = blockIdx.x;
  const int tid = threadIdx.x;
  reinterpret_cast<float2*>(fl)[tid] =
      reinterpret_cast<const float2*>(f + (size_t)node * 512)[tid];
  __syncthreads();
  float* out = nf + (size_t)node * 1792;
  #pragma unroll
  for (int k = 0; k < 7; k++) {
    int o = tid + k * 256;
    float acc = 0.f;
    if (o < 128) {                       // sc_k
      int l = o >> 5, c = o & 31;
      const float* w = Wk + (size_t)(((li*4 + l)*2 + 0)*32 + c) * 32;
      #pragma unroll
      for (int i = 0; i < 32; i++) acc += w[i] * fl[i*16];
    } else if (o < 256) {                // sc_v
      int o2 = o - 128; int l = o2 >> 5, c = o2 & 31;
      const float* w = Wv + (size_t)(((li*4 + l)*2 + 0)*32 + c) * 32;
      #pragma unroll
      for (int i = 0; i < 32; i++) acc += w[i] * fl[i*16];
    } else if (o < 768) {                // id_k
      int o2 = o - 256; int c = o2 >> 4, mg = o2 & 15, l = lof(mg);
      const float* w = Wk + (size_t)(((li*4 + l)*2 + 1)*32 + c) * 32;
      #pragma unroll
      for (int i = 0; i < 32; i++) acc += w[i] * fl[i*16 + mg];
    } else if (o < 1280) {               // id_v
      int o2 = o - 768; int c = o2 >> 4, mg = o2 & 15, l = lof(mg);
      const float* w = Wv + (size_t)(((li*4 + l)*2 + 1)*32 + c) * 32;
      #pragma unroll
      for (int i = 0; i < 32; i++) acc += w[i] * fl[i*16 + mg];
    } else {                             // q
      int o2 = o - 1280; int c = o2 >> 4, mg = o2 & 15, l = lof(mg);
      const float* w = Wq + (size_t)((li*4 + l)*32 + c) * 32;
      #pragma unroll
      for (int i = 0; i < 32; i++) acc += w[i] * fl[i*16 + mg];
    }
    out[o] = acc;
  }
}

// ---------------- fused attention layer: one block per (b, dst) ----------------
__global__ __launch_bounds__(256) void attn_k(
    const float* __restrict__ f, const float* __restrict__ nf,
    float* __restrict__ fnext,
    const float* __restrict__ x, const int* __restrict__ bond,
    const float* __restrict__ rw1, const float* __restrict__ rb1,
    const float* __restrict__ rw2, const float* __restrict__ rb2,
    const float* __restrict__ Wself, const float* __restrict__ gnorm,
    const float* __restrict__ bnorm, int li) {
  __shared__ __align__(16) float Ysh[64][16];     // Y per source; reused as o_lds in epilogue
  __shared__ float rinsh[64][8];                  // dist + 4 bond one-hots
  __shared__ float qsh[32 * 17];                  // q, padded stride 17
  __shared__ __align__(16) float fdst[512];       // dst fiber (Wself skip)
  __shared__ __align__(16) float hmidAll[64][32]; // radial hidden, ALL edges; reused as fac in epilogue
  __shared__ __align__(16) float logitsp[2][4][8][4]; // [buf][e][h][lw] partial logits
  __shared__ __align__(8)  float r23g[2][4][320]; // [buf][e][c*10 + l*2 + p] v-path r

  const int tid = threadIdx.x;
  const int bx  = blockIdx.x;
  const int b = bx >> 6, d = bx & 63;
  const int o0 = 2 * tid;
  const int lw = tid >> 6;              // wave id == degree l of this thread's r-columns
  const int jj = (tid >> 4) & 3;        // radial path 0..3
  const int c0 = o0 & 31;               // even channel of the r-column pair
  const int hH = c0 >> 2;
  const int mgb = mgb_of(lw);
  const int Ml = 2 * lw + 1;

  // ---- block-start loads ----
  {
    const float2 qv = *reinterpret_cast<const float2*>(nf + (size_t)bx * 1792 + 1280 + o0);
    int qc = tid >> 3, qm = 2 * (tid & 7);
    qsh[qc * 17 + qm] = qv.x;
    qsh[qc * 17 + qm + 1] = qv.y;
    *reinterpret_cast<float2*>(fdst + o0) =
        *reinterpret_cast<const float2*>(f + (size_t)bx * 512 + o0);
  }
  if (tid < 64) {               // inline geometry for source s = tid
    const int s = tid;
    const float* xb = x + (size_t)b * 192;
    float xd = xb[d*3+0], yd = xb[d*3+1], zd = xb[d*3+2];
    float dx = xb[s*3+0] - xd, dy = xb[s*3+1] - yd, dz = xb[s*3+2] - zd;
    float dist = sqrtf(dx*dx + dy*dy + dz*dz + 1e-6f);
    float inv = 1.0f / dist;
    float xx = dx*inv, yy = dy*inv, zz = dz*inv;
    float* Y = Ysh[s];
    Y[0]  = 0.28209479177387814f;
    Y[1]  = 0.4886025119029199f * yy;
    Y[2]  = 0.4886025119029199f * zz;
    Y[3]  = 0.4886025119029199f * xx;
    Y[4]  = 1.0925484305920792f * xx * yy;
    Y[5]  = 1.0925484305920792f * yy * zz;
    Y[6]  = 0.31539156525252005f * (3.0f*zz*zz - 1.0f);
    Y[7]  = 1.0925484305920792f * xx * zz;
    Y[8]  = 0.5462742152960396f * (xx*xx - yy*yy);
    Y[9]  = 0.5900435899266435f * yy * (3.0f*xx*xx - yy*yy);
    Y[10] = 2.890611442640554f  * xx * yy * zz;
    Y[11] = 0.4570457994644658f * yy * (5.0f*zz*zz - 1.0f);
    Y[12] = 0.3731763325901154f * zz * (5.0f*zz*zz - 3.0f);
    Y[13] = 0.4570457994644658f * xx * (5.0f*zz*zz - 1.0f);
    Y[14] = 1.445305721320277f  * zz * (xx*xx - yy*yy);
    Y[15] = 0.5900435899266435f * xx * (xx*xx - yy*yy);
    rinsh[s][0] = dist;
    int bt = bond[(size_t)b * 4096 + d * 64 + s];
    bt = bt < 0 ? 0 : (bt > 4 ? 4 : bt);
    rinsh[s][1] = (bt == 1) ? 1.f : 0.f;
    rinsh[s][2] = (bt == 2) ? 1.f : 0.f;
    rinsh[s][3] = (bt == 3) ? 1.f : 0.f;
    rinsh[s][4] = (bt == 4) ? 1.f : 0.f;
  }

  // rw2 columns for this thread's 2 outputs, resident in registers
  float2 w2[32];
  #pragma unroll
  for (int i = 0; i < 32; i++)
    w2[i] = *reinterpret_cast<const float2*>(rw2 + ((size_t)li*32 + i) * 512 + o0);
  const float2 rbv = *reinterpret_cast<const float2*>(rb2 + li * 512 + o0);

  const int ch = tid & 31;              // radial-hidden channel for precompute
  float w1r[5];
  #pragma unroll
  for (int i = 0; i < 5; i++) w1r[i] = rw1[(li*5 + i)*32 + ch];
  const float b1r = rb1[li*32 + ch];

  // o-accumulator slot decode (flat = c*16+mg, slots o0, o0+1)
  const int oc = tid >> 3;
  const int mg0 = 2 * (tid & 7), mg1 = mg0 + 1;
  const int l0 = lof(mg0), l1 = lof(mg1);
  const int ohh = oc >> 2;

  float m_run = -1e30f, l_run = 0.0f;
  float acc0 = 0.0f, acc1 = 0.0f;

  __syncthreads();

  // ---- radial hidden (LN+relu) for ALL 64 edges, all lanes active ----
  #pragma unroll
  for (int p = 0; p < 8; p++) {
    const int e = p * 8 + (tid >> 5);
    float pre = b1r;
    #pragma unroll
    for (int i = 0; i < 5; i++) pre += rinsh[e][i] * w1r[i];
    float mu = pre;
    #pragma unroll
    for (int k = 16; k >= 1; k >>= 1) mu += __shfl_xor(mu, k, 32);
    mu *= 0.03125f;
    float dv = pre - mu;
    float var = dv * dv;
    #pragma unroll
    for (int k = 16; k >= 1; k >>= 1) var += __shfl_xor(var, k, 32);
    var *= 0.03125f;
    hmidAll[e][ch] = fmaxf(dv * rsqrtf(var + 1e-6f), 0.0f);
  }
  __syncthreads();

  for (int g = 0; g < 16; g++) {
    const int sb = g * 4;
    const int buf = g & 1;

    // prefetch id_v operands for step D (latency hides under projection FMAs)
    float2 riv[4];
    #pragma unroll
    for (int e = 0; e < 4; e++)
      riv[e] = *reinterpret_cast<const float2*>(
          nf + (size_t)(b*64 + sb + e)*1792 + 768 + o0);

    // B: r = hmid @ rw2 + rb2 for 4 edges, this thread's 2 columns
    float2 racc[4];
    #pragma unroll
    for (int e = 0; e < 4; e++) racc[e] = rbv;
    #pragma unroll
    for (int e = 0; e < 4; e++) {
      const float4* hp = reinterpret_cast<const float4*>(&hmidAll[sb + e][0]);
      float rx = racc[e].x, ry = racc[e].y;
      #pragma unroll
      for (int i4 = 0; i4 < 8; i4++) {
        float4 h4 = hp[i4];
        float2 wa = w2[i4*4+0], wb = w2[i4*4+1], wc = w2[i4*4+2], wd = w2[i4*4+3];
        rx += h4.x*wa.x + h4.y*wb.x + h4.z*wc.x + h4.w*wd.x;
        ry += h4.x*wa.y + h4.y*wb.y + h4.z*wc.y + h4.w*wd.y;
      }
      racc[e].x = rx; racc[e].y = ry;
    }

    // C: logits partials via shuffle-combine (jj 0,1) / stage v-path r (jj 2,3)
    if (jj <= 1) {
      #pragma unroll
      for (int e = 0; e < 4; e++) {
        const int s = sb + e;
        float pl;
        if (jj == 0) {
          const float2 sck = *reinterpret_cast<const float2*>(
              nf + (size_t)(b*64 + s)*1792 + lw*32 + c0);
          float qy0 = 0.f, qy1 = 0.f;
          for (int m = 0; m < Ml; m++) {
            const float Yv = Ysh[s][mgb + m];
            qy0 += qsh[c0*17 + mgb + m] * Yv;
            qy1 += qsh[(c0+1)*17 + mgb + m] * Yv;
          }
          pl = racc[e].x*sck.x*qy0 + racc[e].y*sck.y*qy1;
        } else {
          const float* idk = nf + (size_t)(b*64 + s)*1792 + 256;
          float a0 = 0.f, a1 = 0.f;
          for (int m = 0; m < Ml; m++) {
            a0 += idk[c0*16 + mgb + m]     * qsh[c0*17 + mgb + m];
            a1 += idk[(c0+1)*16 + mgb + m] * qsh[(c0+1)*17 + mgb + m];
          }
          pl = racc[e].x*a0 + racc[e].y*a1;
        }
        pl += __shfl_xor(pl, 16, 64);   // combine k-scalar + k-identity paths
        pl += __shfl_xor(pl, 1, 64);    // combine the 2 channel-pairs of a head
        if (jj == 0 && (tid & 1) == 0) logitsp[buf][e][hH][lw] = pl;
      }
    } else if (jj == 2) {
      #pragma unroll
      for (int e = 0; e < 4; e++) {
        const int s = sb + e;
        const float2 scv = *reinterpret_cast<const float2*>(
            nf + (size_t)(b*64 + s)*1792 + 128 + lw*32 + c0);
        r23g[buf][e][c0*10 + lw*2]     = racc[e].x * scv.x;
        r23g[buf][e][(c0+1)*10 + lw*2] = racc[e].y * scv.y;
      }
    } else {
      #pragma unroll
      for (int e = 0; e < 4; e++) {
        r23g[buf][e][c0*10 + lw*2 + 1]     = racc[e].x;
        r23g[buf][e][(c0+1)*10 + lw*2 + 1] = racc[e].y;
      }
    }
    __syncthreads();

    // D: online-softmax update of this thread's 2 o-slots
    {
      float lg[4];
      #pragma unroll
      for (int e = 0; e < 4; e++) {
        const int s = sb + e;
        const float4 lp = *reinterpret_cast<const float4*>(&logitsp[buf][e][ohh][0]);
        lg[e] = (s == d) ? -1e9f : (lp.x + lp.y + lp.z + lp.w) * 0.125f;
      }
      float m4 = fmaxf(fmaxf(lg[0], lg[1]), fmaxf(lg[2], lg[3]));
      float m_new = fmaxf(m_run, m4);
      float resc = __expf(m_run - m_new);
      acc0 *= resc; acc1 *= resc; l_run *= resc;
      #pragma unroll
      for (int e = 0; e < 4; e++) {
        const int s = sb + e;
        float w = __expf(lg[e] - m_new);
        l_run += w;
        const float2 ra = *reinterpret_cast<const float2*>(&r23g[buf][e][oc*10 + l0*2]);
        const float2 rb = *reinterpret_cast<const float2*>(&r23g[buf][e][oc*10 + l1*2]);
        acc0 += w * (ra.x * Ysh[s][mg0] + ra.y * riv[e].x);
        acc1 += w * (rb.x * Ysh[s][mg1] + rb.y * riv[e].y);
      }
      m_run = m_new;
    }
  }
  __syncthreads();   // protect Ysh before reuse as osh

  // ---- epilogue: normalize, Wself skip, NormSE3 gate, write ----
  const float invl = 1.0f / l_run;
  acc0 *= invl; acc1 *= invl;
  {
    const float* w0 = Wself + (size_t)((li*4 + l0)*32 + oc) * 32;
    const float* w1 = Wself + (size_t)((li*4 + l1)*32 + oc) * 32;
    #pragma unroll
    for (int i = 0; i < 32; i++) {
      acc0 += w0[i] * fdst[i*16 + mg0];
      acc1 += w1[i] * fdst[i*16 + mg1];
    }
  }
  float* osh = &Ysh[0][0];    // reuse
  osh[o0] = acc0; osh[o0 + 1] = acc1;
  __syncthreads();
  if (tid < 128) {
    const int c2 = tid >> 2, l2 = tid & 3;
    const int mb = mgb_of(l2), M2 = 2*l2 + 1;
    float ss = 0.f;
    for (int m = 0; m < M2; m++) { float v = osh[c2*16 + mb + m]; ss += v*v; }
    const float nrm = sqrtf(ss + 1e-6f);
    const float gg = gnorm[(li*4 + l2)*32 + c2];
    const float bb = bnorm[(li*4 + l2)*32 + c2];
    const float sg = fmaxf(gg*nrm + bb, 0.f);
    (&hmidAll[0][0])[c2*4 + l2] = sg / nrm;
  }
  __syncthreads();
  const float fac0 = (&hmidAll[0][0])[oc*4 + l0];
  const float fac1 = (&hmidAll[0][0])[oc*4 + l1];
  *reinterpret_cast<float2*>(fnext + (size_t)bx * 512 + o0) =
      make_float2(acc0 * fac0, acc1 * fac1);
}

// ---------------- readout: invariant norms -> mean over nodes -> Wfinal ----------------
__global__ __launch_bounds__(256) void readout_k(const float* __restrict__ f,
    const float* __restrict__ Wfinal, const float* __restrict__ bfinal,
    float* __restrict__ out) {
  __shared__ float invs[2][128];
  __shared__ float inv1[128];
  const int b = blockIdx.x;
  const int tid = threadIdx.x;
  const int j = tid & 127, half = tid >> 7;
  float p = 0.f;
  for (int n = half*32; n < half*32 + 32; n++) {
    const float* fn = f + (size_t)(b*64 + n) * 512;
    float v;
    if (j < 32) {
      v = fn[j*16];
    } else {
      int l = j >> 5, c = j & 31;
      int mb = mgb_of(l), M = 2*l + 1;
      float ss = 0.f;
      for (int m = 0; m < M; m++) { float t = fn[c*16 + mb + m]; ss += t*t; }
      v = sqrtf(ss + 1e-6f);
    }
    p += v;
  }
  invs[half][j] = p;
  __syncthreads();
  if (tid < 128) inv1[tid] = (invs[0][tid] + invs[1][tid]) * (1.0f / 64.0f);
  __syncthreads();
  if (tid < 128) {
    float acc = bfinal[tid];
    for (int k = 0; k < 128; k++) acc += inv1[k] * Wfinal[k*128 + tid];
    out[b*128 + tid] = acc;
  }
}

extern "C" void kernel_launch(void* const* d_in, const int* in_sizes, int n_in,
                              void* d_out, int out_size, void* d_ws, size_t ws_size,
                              hipStream_t stream) {
  (void)in_sizes; (void)n_in; (void)out_size; (void)ws_size;
  const float* h      = (const float*)d_in[0];
  const float* x      = (const float*)d_in[1];
  const int*   bond   = (const int*)d_in[2];
  const float* Wemb   = (const float*)d_in[3];
  const float* rw1    = (const float*)d_in[4];
  const float* rb1    = (const float*)d_in[5];
  const float* rw2    = (const float*)d_in[6];
  const float* rb2    = (const float*)d_in[7];
  const float* Wk     = (const float*)d_in[8];
  const float* Wv     = (const float*)d_in[9];
  const float* Wq     = (const float*)d_in[10];
  const float* Wself  = (const float*)d_in[11];
  const float* gnorm  = (const float*)d_in[12];
  const float* bnorm  = (const float*)d_in[13];
  const float* Wfinal = (const float*)d_in[14];
  const float* bfinal = (const float*)d_in[15];
  float* out = (float*)d_out;

  float* ws = (float*)d_ws;
  float* fA = ws;                       // 524288 floats
  float* fB = ws + 524288;              // 524288 floats
  float* nf = ws + 2 * 524288;          // 1024*1792 floats

  embed_k<<<2048, 256, 0, stream>>>(h, Wemb, fA);

  float* fc = fA; float* fn2 = fB;
  for (int li = 0; li < 4; li++) {
    nodefeats_k<<<1024, 256, 0, stream>>>(fc, Wk, Wv, Wq, nf, li);
    attn_k<<<1024, 256, 0, stream>>>(fc, nf, fn2, x, bond,
                                     rw1, rb1, rw2, rb2, Wself, gnorm, bnorm, li);
    float* t = fc; fc = fn2; fn2 = t;
  }

  readout_k<<<16, 256, 0, stream>>>(fc, Wfinal, bfinal, out);
}

// Round 4
// 988.784 us; speedup vs baseline: 1.8107x; 1.1863x over previous
//
#include <hip/hip_runtime.h>

// SE(3)-Transformer backbone, fp32, MI355X.
// Dims: B=16 N=64 FIN=16 C=32 D=4 (mg: l0=1, l1=3, l2=5, l3=7 -> 16) L=4 H=8 hd=4
// f layout: [b*64+n][c][mg] flat, 512 floats per node.
// nodefeats layout per node (1792 floats):
//   +0    sc_k[l*32+c]  (128)
//   +128  sc_v[l*32+c]  (128)
//   +256  id_k[c*16+mg] (512)
//   +768  id_v[c*16+mg] (512)
//   +1280 q   [c*16+mg] (512)
//
// Round-2 lesson: NO min-waves arg on __launch_bounds__ (spills w2 -> 1GB scratch traffic).
// Round-3 lesson: kernel is latency-bound (VALUBusy 25%, occ 24%), not LDS/atomic-bound.
//   -> Round 4: 4-way source-split with partial-softmax (flash-style), combine kernel.

__device__ __forceinline__ int lof(int mg)   { return (mg==0)?0:((mg<4)?1:((mg<9)?2:3)); }
__device__ __forceinline__ int mgb_of(int l) { return (l==0)?0:((l==1)?1:((l==2)?4:9)); }

// ---------------- embed: f0 = h @ Wemb, higher degrees zero ----------------
__global__ __launch_bounds__(256) void embed_k(const float* __restrict__ h,
                                               const float* __restrict__ Wemb,
                                               float* __restrict__ f) {
  int idx = blockIdx.x * 256 + threadIdx.x;   // covers 16*64*512 = 524288
  int node = idx >> 9;
  int rem  = idx & 511;
  int c = rem >> 4, mg = rem & 15;
  float v = 0.f;
  if (mg == 0) {
    const float* hh = h + node * 16;
    #pragma unroll
    for (int i = 0; i < 16; i++) v += hh[i] * Wemb[i * 32 + c];
  }
  f[idx] = v;
}

// ---------------- per-node K/V/Q projections ----------------
__global__ __launch_bounds__(256) void nodefeats_k(const float* __restrict__ f,
    const float* __restrict__ Wk, const float* __restrict__ Wv,
    const float* __restrict__ Wq, float* __restrict__ nf, int li) {
  __shared__ __align__(16) float fl[512];
  const int node = blockIdx.x;
  const int tid = threadIdx.x;
  reinterpret_cast<float2*>(fl)[tid] =
      reinterpret_cast<const float2*>(f + (size_t)node * 512)[tid];
  __syncthreads();
  float* out = nf + (size_t)node * 1792;
  #pragma unroll
  for (int k = 0; k < 7; k++) {
    int o = tid + k * 256;
    float acc = 0.f;
    if (o < 128) {                       // sc_k
      int l = o >> 5, c = o & 31;
      const float* w = Wk + (size_t)(((li*4 + l)*2 + 0)*32 + c) * 32;
      #pragma unroll
      for (int i = 0; i < 32; i++) acc += w[i] * fl[i*16];
    } else if (o < 256) {                // sc_v
      int o2 = o - 128; int l = o2 >> 5, c = o2 & 31;
      const float* w = Wv + (size_t)(((li*4 + l)*2 + 0)*32 + c) * 32;
      #pragma unroll
      for (int i = 0; i < 32; i++) acc += w[i] * fl[i*16];
    } else if (o < 768) {                // id_k
      int o2 = o - 256; int c = o2 >> 4, mg = o2 & 15, l = lof(mg);
      const float* w = Wk + (size_t)(((li*4 + l)*2 + 1)*32 + c) * 32;
      #pragma unroll
      for (int i = 0; i < 32; i++) acc += w[i] * fl[i*16 + mg];
    } else if (o < 1280) {               // id_v
      int o2 = o - 768; int c = o2 >> 4, mg = o2 & 15, l = lof(mg);
      const float* w = Wv + (size_t)(((li*4 + l)*2 + 1)*32 + c) * 32;
      #pragma unroll
      for (int i = 0; i < 32; i++) acc += w[i] * fl[i*16 + mg];
    } else {                             // q
      int o2 = o - 1280; int c = o2 >> 4, mg = o2 & 15, l = lof(mg);
      const float* w = Wq + (size_t)((li*4 + l)*32 + c) * 32;
      #pragma unroll
      for (int i = 0; i < 32; i++) acc += w[i] * fl[i*16 + mg];
    }
    out[o] = acc;
  }
}

// ------- fused attention partial: one block per (b, dst, source-quarter) -------
// Emits unnormalized online-softmax partials: pml[bx][h*2+{m,l}], pacc[bx][512].
__global__ __launch_bounds__(256) void attn_k(
    const float* __restrict__ nf,
    float* __restrict__ pml, float* __restrict__ pacc,
    const float* __restrict__ x, const int* __restrict__ bond,
    const float* __restrict__ rw1, const float* __restrict__ rb1,
    const float* __restrict__ rw2, const float* __restrict__ rb2, int li) {
  __shared__ __align__(16) float Ysh[16][16];     // Y per local source
  __shared__ float rinsh[16][8];                  // dist + 4 bond one-hots
  __shared__ float qsh[32 * 17];                  // q, padded stride 17
  __shared__ __align__(16) float hmidAll[16][32]; // radial hidden, this quarter's edges
  __shared__ __align__(16) float logitsp[2][4][8][4]; // [buf][e][h][lw] partial logits
  __shared__ __align__(8)  float r23g[2][4][320]; // [buf][e][c*10 + l*2 + p] v-path r

  const int tid = threadIdx.x;
  const int bx  = blockIdx.x;          // 4096 = (b*64+d)*4 + sp
  const int bd  = bx >> 2, sp = bx & 3;
  const int b = bd >> 6, d = bd & 63;
  const int s0g = sp * 16;             // first global source of this quarter
  const int o0 = 2 * tid;
  const int lw = tid >> 6;              // wave id == degree l of this thread's r-columns
  const int jj = (tid >> 4) & 3;        // radial path 0..3
  const int c0 = o0 & 31;               // even channel of the r-column pair
  const int hH = c0 >> 2;
  const int mgb = mgb_of(lw);
  const int Ml = 2 * lw + 1;

  // ---- block-start loads ----
  {
    const float2 qv = *reinterpret_cast<const float2*>(nf + (size_t)bd * 1792 + 1280 + o0);
    int qc = tid >> 3, qm = 2 * (tid & 7);
    qsh[qc * 17 + qm] = qv.x;
    qsh[qc * 17 + qm + 1] = qv.y;
  }
  if (tid < 16) {               // inline geometry for local source s = tid
    const int s = tid;
    const int sg = s0g + s;
    const float* xb = x + (size_t)b * 192;
    float xd = xb[d*3+0], yd = xb[d*3+1], zd = xb[d*3+2];
    float dx = xb[sg*3+0] - xd, dy = xb[sg*3+1] - yd, dz = xb[sg*3+2] - zd;
    float dist = sqrtf(dx*dx + dy*dy + dz*dz + 1e-6f);
    float inv = 1.0f / dist;
    float xx = dx*inv, yy = dy*inv, zz = dz*inv;
    float* Y = Ysh[s];
    Y[0]  = 0.28209479177387814f;
    Y[1]  = 0.4886025119029199f * yy;
    Y[2]  = 0.4886025119029199f * zz;
    Y[3]  = 0.4886025119029199f * xx;
    Y[4]  = 1.0925484305920792f * xx * yy;
    Y[5]  = 1.0925484305920792f * yy * zz;
    Y[6]  = 0.31539156525252005f * (3.0f*zz*zz - 1.0f);
    Y[7]  = 1.0925484305920792f * xx * zz;
    Y[8]  = 0.5462742152960396f * (xx*xx - yy*yy);
    Y[9]  = 0.5900435899266435f * yy * (3.0f*xx*xx - yy*yy);
    Y[10] = 2.890611442640554f  * xx * yy * zz;
    Y[11] = 0.4570457994644658f * yy * (5.0f*zz*zz - 1.0f);
    Y[12] = 0.3731763325901154f * zz * (5.0f*zz*zz - 3.0f);
    Y[13] = 0.4570457994644658f * xx * (5.0f*zz*zz - 1.0f);
    Y[14] = 1.445305721320277f  * zz * (xx*xx - yy*yy);
    Y[15] = 0.5900435899266435f * xx * (xx*xx - yy*yy);
    rinsh[s][0] = dist;
    int bt = bond[(size_t)b * 4096 + d * 64 + sg];
    bt = bt < 0 ? 0 : (bt > 4 ? 4 : bt);
    rinsh[s][1] = (bt == 1) ? 1.f : 0.f;
    rinsh[s][2] = (bt == 2) ? 1.f : 0.f;
    rinsh[s][3] = (bt == 3) ? 1.f : 0.f;
    rinsh[s][4] = (bt == 4) ? 1.f : 0.f;
  }

  // rw2 columns for this thread's 2 outputs, resident in registers
  float2 w2[32];
  #pragma unroll
  for (int i = 0; i < 32; i++)
    w2[i] = *reinterpret_cast<const float2*>(rw2 + ((size_t)li*32 + i) * 512 + o0);
  const float2 rbv = *reinterpret_cast<const float2*>(rb2 + li * 512 + o0);

  const int ch = tid & 31;              // radial-hidden channel for precompute
  float w1r[5];
  #pragma unroll
  for (int i = 0; i < 5; i++) w1r[i] = rw1[(li*5 + i)*32 + ch];
  const float b1r = rb1[li*32 + ch];

  // o-accumulator slot decode (flat = c*16+mg, slots o0, o0+1)
  const int oc = tid >> 3;
  const int mg0 = 2 * (tid & 7), mg1 = mg0 + 1;
  const int l0 = lof(mg0), l1 = lof(mg1);
  const int ohh = oc >> 2;

  float m_run = -1e30f, l_run = 0.0f;
  float acc0 = 0.0f, acc1 = 0.0f;

  __syncthreads();

  // ---- radial hidden (LN+relu) for this quarter's 16 edges ----
  #pragma unroll
  for (int p = 0; p < 2; p++) {
    const int e = p * 8 + (tid >> 5);
    float pre = b1r;
    #pragma unroll
    for (int i = 0; i < 5; i++) pre += rinsh[e][i] * w1r[i];
    float mu = pre;
    #pragma unroll
    for (int k = 16; k >= 1; k >>= 1) mu += __shfl_xor(mu, k, 32);
    mu *= 0.03125f;
    float dv = pre - mu;
    float var = dv * dv;
    #pragma unroll
    for (int k = 16; k >= 1; k >>= 1) var += __shfl_xor(var, k, 32);
    var *= 0.03125f;
    hmidAll[e][ch] = fmaxf(dv * rsqrtf(var + 1e-6f), 0.0f);
  }
  __syncthreads();

  for (int g = 0; g < 4; g++) {
    const int sb = g * 4;               // local source base
    const int buf = g & 1;

    // prefetch id_v operands for step D
    float2 riv[4];
    #pragma unroll
    for (int e = 0; e < 4; e++)
      riv[e] = *reinterpret_cast<const float2*>(
          nf + (size_t)(b*64 + s0g + sb + e)*1792 + 768 + o0);

    // B: r = hmid @ rw2 + rb2 for 4 edges, this thread's 2 columns
    float2 racc[4];
    #pragma unroll
    for (int e = 0; e < 4; e++) racc[e] = rbv;
    #pragma unroll
    for (int e = 0; e < 4; e++) {
      const float4* hp = reinterpret_cast<const float4*>(&hmidAll[sb + e][0]);
      float rx = racc[e].x, ry = racc[e].y;
      #pragma unroll
      for (int i4 = 0; i4 < 8; i4++) {
        float4 h4 = hp[i4];
        float2 wa = w2[i4*4+0], wb = w2[i4*4+1], wc = w2[i4*4+2], wd = w2[i4*4+3];
        rx += h4.x*wa.x + h4.y*wb.x + h4.z*wc.x + h4.w*wd.x;
        ry += h4.x*wa.y + h4.y*wb.y + h4.z*wc.y + h4.w*wd.y;
      }
      racc[e].x = rx; racc[e].y = ry;
    }

    // C: logits partials via shuffle-combine (jj 0,1) / stage v-path r (jj 2,3)
    if (jj <= 1) {
      #pragma unroll
      for (int e = 0; e < 4; e++) {
        const int sl = sb + e;
        const int sg = s0g + sl;
        float pl;
        if (jj == 0) {
          const float2 sck = *reinterpret_cast<const float2*>(
              nf + (size_t)(b*64 + sg)*1792 + lw*32 + c0);
          float qy0 = 0.f, qy1 = 0.f;
          for (int m = 0; m < Ml; m++) {
            const float Yv = Ysh[sl][mgb + m];
            qy0 += qsh[c0*17 + mgb + m] * Yv;
            qy1 += qsh[(c0+1)*17 + mgb + m] * Yv;
          }
          pl = racc[e].x*sck.x*qy0 + racc[e].y*sck.y*qy1;
        } else {
          const float* idk = nf + (size_t)(b*64 + sg)*1792 + 256;
          float a0 = 0.f, a1 = 0.f;
          for (int m = 0; m < Ml; m++) {
            a0 += idk[c0*16 + mgb + m]     * qsh[c0*17 + mgb + m];
            a1 += idk[(c0+1)*16 + mgb + m] * qsh[(c0+1)*17 + mgb + m];
          }
          pl = racc[e].x*a0 + racc[e].y*a1;
        }
        pl += __shfl_xor(pl, 16, 64);   // combine k-scalar + k-identity paths
        pl += __shfl_xor(pl, 1, 64);    // combine the 2 channel-pairs of a head
        if (jj == 0 && (tid & 1) == 0) logitsp[buf][e][hH][lw] = pl;
      }
    } else if (jj == 2) {
      #pragma unroll
      for (int e = 0; e < 4; e++) {
        const int sg = s0g + sb + e;
        const float2 scv = *reinterpret_cast<const float2*>(
            nf + (size_t)(b*64 + sg)*1792 + 128 + lw*32 + c0);
        r23g[buf][e][c0*10 + lw*2]     = racc[e].x * scv.x;
        r23g[buf][e][(c0+1)*10 + lw*2] = racc[e].y * scv.y;
      }
    } else {
      #pragma unroll
      for (int e = 0; e < 4; e++) {
        r23g[buf][e][c0*10 + lw*2 + 1]     = racc[e].x;
        r23g[buf][e][(c0+1)*10 + lw*2 + 1] = racc[e].y;
      }
    }
    __syncthreads();

    // D: online-softmax update of this thread's 2 o-slots
    {
      float lg[4];
      #pragma unroll
      for (int e = 0; e < 4; e++) {
        const int sg = s0g + sb + e;
        const float4 lp = *reinterpret_cast<const float4*>(&logitsp[buf][e][ohh][0]);
        lg[e] = (sg == d) ? -1e9f : (lp.x + lp.y + lp.z + lp.w) * 0.125f;
      }
      float m4 = fmaxf(fmaxf(lg[0], lg[1]), fmaxf(lg[2], lg[3]));
      float m_new = fmaxf(m_run, m4);
      float resc = __expf(m_run - m_new);
      acc0 *= resc; acc1 *= resc; l_run *= resc;
      #pragma unroll
      for (int e = 0; e < 4; e++) {
        const int sl = sb + e;
        float w = __expf(lg[e] - m_new);
        l_run += w;
        const float2 ra = *reinterpret_cast<const float2*>(&r23g[buf][e][oc*10 + l0*2]);
        const float2 rb = *reinterpret_cast<const float2*>(&r23g[buf][e][oc*10 + l1*2]);
        acc0 += w * (ra.x * Ysh[sl][mg0] + ra.y * riv[e].x);
        acc1 += w * (rb.x * Ysh[sl][mg1] + rb.y * riv[e].y);
      }
      m_run = m_new;
    }
  }

  // ---- emit partials (unnormalized) ----
  if ((tid & 31) == 0) {
    pml[(size_t)bx * 16 + ohh * 2]     = m_run;
    pml[(size_t)bx * 16 + ohh * 2 + 1] = l_run;
  }
  *reinterpret_cast<float2*>(pacc + (size_t)bx * 512 + o0) = make_float2(acc0, acc1);
}

// ------- combine partials + epilogue (Wself skip, NormSE3 gate) -------
__global__ __launch_bounds__(256) void combine_k(
    const float* __restrict__ f, const float* __restrict__ pml,
    const float* __restrict__ pacc, float* __restrict__ fnext,
    const float* __restrict__ Wself, const float* __restrict__ gnorm,
    const float* __restrict__ bnorm, int li) {
  __shared__ __align__(16) float fdst[512];
  __shared__ __align__(16) float osh[512];
  __shared__ float facsh[128];
  __shared__ float mls[4][16];

  const int bd = blockIdx.x;           // b*64 + d
  const int tid = threadIdx.x;
  const int o0 = 2 * tid;
  const int oc = tid >> 3;
  const int mg0 = 2 * (tid & 7), mg1 = mg0 + 1;
  const int l0 = lof(mg0), l1 = lof(mg1);
  const int ohh = oc >> 2;

  *reinterpret_cast<float2*>(fdst + o0) =
      *reinterpret_cast<const float2*>(f + (size_t)bd * 512 + o0);
  if (tid < 64) {
    int sp = tid >> 4, i = tid & 15;
    mls[sp][i] = pml[(size_t)(bd * 4 + sp) * 16 + i];
  }
  __syncthreads();

  float mstar = fmaxf(fmaxf(mls[0][ohh*2], mls[1][ohh*2]),
                      fmaxf(mls[2][ohh*2], mls[3][ohh*2]));
  float wsum = 0.f, a0 = 0.f, a1 = 0.f;
  #pragma unroll
  for (int sp = 0; sp < 4; sp++) {
    float ew = __expf(mls[sp][ohh*2] - mstar);
    wsum += mls[sp][ohh*2 + 1] * ew;
    const float2 pa = *reinterpret_cast<const float2*>(
        pacc + (size_t)(bd * 4 + sp) * 512 + o0);
    a0 += ew * pa.x;
    a1 += ew * pa.y;
  }
  const float invw = 1.0f / wsum;
  a0 *= invw; a1 *= invw;

  // Wself skip
  {
    const float* w0 = Wself + (size_t)((li*4 + l0)*32 + oc) * 32;
    const float* w1 = Wself + (size_t)((li*4 + l1)*32 + oc) * 32;
    #pragma unroll
    for (int i = 0; i < 32; i++) {
      a0 += w0[i] * fdst[i*16 + mg0];
      a1 += w1[i] * fdst[i*16 + mg1];
    }
  }
  osh[o0] = a0; osh[o0 + 1] = a1;
  __syncthreads();
  if (tid < 128) {
    const int c2 = tid >> 2, l2 = tid & 3;
    const int mb = mgb_of(l2), M2 = 2*l2 + 1;
    float ss = 0.f;
    for (int m = 0; m < M2; m++) { float v = osh[c2*16 + mb + m]; ss += v*v; }
    const float nrm = sqrtf(ss + 1e-6f);
    const float gg = gnorm[(li*4 + l2)*32 + c2];
    const float bb = bnorm[(li*4 + l2)*32 + c2];
    const float sg = fmaxf(gg*nrm + bb, 0.f);
    facsh[c2*4 + l2] = sg / nrm;
  }
  __syncthreads();
  *reinterpret_cast<float2*>(fnext + (size_t)bd * 512 + o0) =
      make_float2(a0 * facsh[oc*4 + l0], a1 * facsh[oc*4 + l1]);
}

// ---------------- readout: invariant norms -> mean over nodes -> Wfinal ----------------
__global__ __launch_bounds__(256) void readout_k(const float* __restrict__ f,
    const float* __restrict__ Wfinal, const float* __restrict__ bfinal,
    float* __restrict__ out) {
  __shared__ float invs[2][128];
  __shared__ float inv1[128];
  const int b = blockIdx.x;
  const int tid = threadIdx.x;
  const int j = tid & 127, half = tid >> 7;
  float p = 0.f;
  for (int n = half*32; n < half*32 + 32; n++) {
    const float* fn = f + (size_t)(b*64 + n) * 512;
    float v;
    if (j < 32) {
      v = fn[j*16];
    } else {
      int l = j >> 5, c = j & 31;
      int mb = mgb_of(l), M = 2*l + 1;
      float ss = 0.f;
      for (int m = 0; m < M; m++) { float t = fn[c*16 + mb + m]; ss += t*t; }
      v = sqrtf(ss + 1e-6f);
    }
    p += v;
  }
  invs[half][j] = p;
  __syncthreads();
  if (tid < 128) inv1[tid] = (invs[0][tid] + invs[1][tid]) * (1.0f / 64.0f);
  __syncthreads();
  if (tid < 128) {
    float acc = bfinal[tid];
    for (int k = 0; k < 128; k++) acc += inv1[k] * Wfinal[k*128 + tid];
    out[b*128 + tid] = acc;
  }
}

extern "C" void kernel_launch(void* const* d_in, const int* in_sizes, int n_in,
                              void* d_out, int out_size, void* d_ws, size_t ws_size,
                              hipStream_t stream) {
  (void)in_sizes; (void)n_in; (void)out_size; (void)ws_size;
  const float* h      = (const float*)d_in[0];
  const float* x      = (const float*)d_in[1];
  const int*   bond   = (const int*)d_in[2];
  const float* Wemb   = (const float*)d_in[3];
  const float* rw1    = (const float*)d_in[4];
  const float* rb1    = (const float*)d_in[5];
  const float* rw2    = (const float*)d_in[6];
  const float* rb2    = (const float*)d_in[7];
  const float* Wk     = (const float*)d_in[8];
  const float* Wv     = (const float*)d_in[9];
  const float* Wq     = (const float*)d_in[10];
  const float* Wself  = (const float*)d_in[11];
  const float* gnorm  = (const float*)d_in[12];
  const float* bnorm  = (const float*)d_in[13];
  const float* Wfinal = (const float*)d_in[14];
  const float* bfinal = (const float*)d_in[15];
  float* out = (float*)d_out;

  float* ws = (float*)d_ws;
  float* fA   = ws;                         // 524288 floats
  float* fB   = ws + 524288;                // 524288 floats
  float* nf   = ws + 2 * 524288;            // 1024*1792 = 1835008 floats
  float* pml  = ws + 2 * 524288 + 1835008;  // 4096*16 = 65536 floats
  float* pacc = pml + 65536;                // 4096*512 = 2097152 floats

  embed_k<<<2048, 256, 0, stream>>>(h, Wemb, fA);

  float* fc = fA; float* fn2 = fB;
  for (int li = 0; li < 4; li++) {
    nodefeats_k<<<1024, 256, 0, stream>>>(fc, Wk, Wv, Wq, nf, li);
    attn_k<<<4096, 256, 0, stream>>>(nf, pml, pacc, x, bond,
                                     rw1, rb1, rw2, rb2, li);
    combine_k<<<1024, 256, 0, stream>>>(fc, pml, pacc, fn2,
                                        Wself, gnorm, bnorm, li);
    float* t = fc; fc = fn2; fn2 = t;
  }

  readout_k<<<16, 256, 0, stream>>>(fc, Wfinal, bfinal, out);
}

// Round 5
// 678.559 us; speedup vs baseline: 2.6385x; 1.4572x over previous
//
#include <hip/hip_runtime.h>

// SE(3)-Transformer backbone, fp32, MI355X.
// Dims: B=16 N=64 FIN=16 C=32 D=4 (mg: l0=1, l1=3, l2=5, l3=7 -> 16) L=4 H=8 hd=4
// f layout: [b*64+n][c][mg] flat, 512 floats per node.
// nodefeats layout per node (1792 floats):
//   +0    sc_k[l*32+c]  (128)
//   +128  sc_v[l*32+c]  (128)
//   +256  id_k[c*16+mg] (512)
//   +768  id_v[c*16+mg] (512)
//   +1280 q   [c*16+mg] (512)
//
// Round-2 lesson: NO min-waves arg on __launch_bounds__ (spills w2 -> 1GB scratch traffic).
// Round-3 lesson: latency-bound -> round-4 4-way flash-style source split.
// Round-4 lesson: ~5200 VALU inst/thread vs ~1100 useful FMA; overhead = variable-M
//   C-loops + logitsp LDS round-trip + 64-bit addr math. Round 5: slot-homogeneous
//   fused C+D with float4 r-staging and butterfly-shuffle logits.

__device__ __forceinline__ int lof(int mg)   { return (mg==0)?0:((mg<4)?1:((mg<9)?2:3)); }
__device__ __forceinline__ int mgb_of(int l) { return (l==0)?0:((l==1)?1:((l==2)?4:9)); }

// ---------------- embed: f0 = h @ Wemb, higher degrees zero ----------------
__global__ __launch_bounds__(256) void embed_k(const float* __restrict__ h,
                                               const float* __restrict__ Wemb,
                                               float* __restrict__ f) {
  int idx = blockIdx.x * 256 + threadIdx.x;   // covers 16*64*512 = 524288
  int node = idx >> 9;
  int rem  = idx & 511;
  int c = rem >> 4, mg = rem & 15;
  float v = 0.f;
  if (mg == 0) {
    const float* hh = h + node * 16;
    #pragma unroll
    for (int i = 0; i < 16; i++) v += hh[i] * Wemb[i * 32 + c];
  }
  f[idx] = v;
}

// ---------------- per-node K/V/Q projections ----------------
__global__ __launch_bounds__(256) void nodefeats_k(const float* __restrict__ f,
    const float* __restrict__ Wk, const float* __restrict__ Wv,
    const float* __restrict__ Wq, float* __restrict__ nf, int li) {
  __shared__ __align__(16) float fl[512];
  const int node = blockIdx.x;
  const int tid = threadIdx.x;
  reinterpret_cast<float2*>(fl)[tid] =
      reinterpret_cast<const float2*>(f + (size_t)node * 512)[tid];
  __syncthreads();
  float* out = nf + (size_t)node * 1792;
  #pragma unroll
  for (int k = 0; k < 7; k++) {
    int o = tid + k * 256;
    float acc = 0.f;
    if (o < 128) {                       // sc_k
      int l = o >> 5, c = o & 31;
      const float* w = Wk + (size_t)(((li*4 + l)*2 + 0)*32 + c) * 32;
      #pragma unroll
      for (int i = 0; i < 32; i++) acc += w[i] * fl[i*16];
    } else if (o < 256) {                // sc_v
      int o2 = o - 128; int l = o2 >> 5, c = o2 & 31;
      const float* w = Wv + (size_t)(((li*4 + l)*2 + 0)*32 + c) * 32;
      #pragma unroll
      for (int i = 0; i < 32; i++) acc += w[i] * fl[i*16];
    } else if (o < 768) {                // id_k
      int o2 = o - 256; int c = o2 >> 4, mg = o2 & 15, l = lof(mg);
      const float* w = Wk + (size_t)(((li*4 + l)*2 + 1)*32 + c) * 32;
      #pragma unroll
      for (int i = 0; i < 32; i++) acc += w[i] * fl[i*16 + mg];
    } else if (o < 1280) {               // id_v
      int o2 = o - 768; int c = o2 >> 4, mg = o2 & 15, l = lof(mg);
      const float* w = Wv + (size_t)(((li*4 + l)*2 + 1)*32 + c) * 32;
      #pragma unroll
      for (int i = 0; i < 32; i++) acc += w[i] * fl[i*16 + mg];
    } else {                             // q
      int o2 = o - 1280; int c = o2 >> 4, mg = o2 & 15, l = lof(mg);
      const float* w = Wq + (size_t)((li*4 + l)*32 + c) * 32;
      #pragma unroll
      for (int i = 0; i < 32; i++) acc += w[i] * fl[i*16 + mg];
    }
    out[o] = acc;
  }
}

// ------- fused attention partial: one block per (b, dst, source-quarter) -------
// Emits unnormalized online-softmax partials: pml[bx][h*2+{m,l}], pacc[bx][512].
__global__ __launch_bounds__(256) void attn_k(
    const float* __restrict__ nf,
    float* __restrict__ pml, float* __restrict__ pacc,
    const float* __restrict__ x, const int* __restrict__ bond,
    const float* __restrict__ rw1, const float* __restrict__ rb1,
    const float* __restrict__ rw2, const float* __restrict__ rb2, int li) {
  __shared__ __align__(16) float Ysh[16][16];     // Y per local source
  __shared__ float rinsh[16][8];                  // dist + 4 bond one-hots
  __shared__ __align__(16) float hmidAll[16][32]; // radial hidden, this quarter's edges
  // r staging: [buf][edge 0..3][c*22 + l*4 + path], path = {r0*sck, r1, r2*scv, r3}
  __shared__ __align__(16) float r4g[2][2816];    // 4 edges * 704 floats

  const int tid = threadIdx.x;
  const int bx  = blockIdx.x;          // 4096 = (b*64+d)*4 + sp
  const int bd  = bx >> 2, sp = bx & 3;
  const int b = bd >> 6, d = bd & 63;
  const int s0g = sp * 16;             // first global source of this quarter
  const int o0 = 2 * tid;
  const int lw = tid >> 6;              // wave id == degree l of this thread's r-columns
  const int jj = (tid >> 4) & 3;        // radial path 0..3
  const int c0 = o0 & 31;               // even channel of the r-column pair

  // o-accumulator slot decode (flat = c*16+mg, slots o0, o0+1)
  const int oc = tid >> 3;
  const int mg0 = 2 * (tid & 7), mg1 = mg0 + 1;
  const int l0 = lof(mg0), l1 = lof(mg1);
  const int ohh = oc >> 2;

  // per-slot q, resident in registers (replaces qsh)
  const float2 qv = *reinterpret_cast<const float2*>(nf + (size_t)bd * 1792 + 1280 + o0);

  if (tid < 16) {               // inline geometry for local source s = tid
    const int s = tid;
    const int sg = s0g + s;
    const float* xb = x + (size_t)b * 192;
    float xd = xb[d*3+0], yd = xb[d*3+1], zd = xb[d*3+2];
    float dx = xb[sg*3+0] - xd, dy = xb[sg*3+1] - yd, dz = xb[sg*3+2] - zd;
    float dist = sqrtf(dx*dx + dy*dy + dz*dz + 1e-6f);
    float inv = 1.0f / dist;
    float xx = dx*inv, yy = dy*inv, zz = dz*inv;
    float* Y = Ysh[s];
    Y[0]  = 0.28209479177387814f;
    Y[1]  = 0.4886025119029199f * yy;
    Y[2]  = 0.4886025119029199f * zz;
    Y[3]  = 0.4886025119029199f * xx;
    Y[4]  = 1.0925484305920792f * xx * yy;
    Y[5]  = 1.0925484305920792f * yy * zz;
    Y[6]  = 0.31539156525252005f * (3.0f*zz*zz - 1.0f);
    Y[7]  = 1.0925484305920792f * xx * zz;
    Y[8]  = 0.5462742152960396f * (xx*xx - yy*yy);
    Y[9]  = 0.5900435899266435f * yy * (3.0f*xx*xx - yy*yy);
    Y[10] = 2.890611442640554f  * xx * yy * zz;
    Y[11] = 0.4570457994644658f * yy * (5.0f*zz*zz - 1.0f);
    Y[12] = 0.3731763325901154f * zz * (5.0f*zz*zz - 3.0f);
    Y[13] = 0.4570457994644658f * xx * (5.0f*zz*zz - 1.0f);
    Y[14] = 1.445305721320277f  * zz * (xx*xx - yy*yy);
    Y[15] = 0.5900435899266435f * xx * (xx*xx - yy*yy);
    rinsh[s][0] = dist;
    int bt = bond[(size_t)b * 4096 + d * 64 + sg];
    bt = bt < 0 ? 0 : (bt > 4 ? 4 : bt);
    rinsh[s][1] = (bt == 1) ? 1.f : 0.f;
    rinsh[s][2] = (bt == 2) ? 1.f : 0.f;
    rinsh[s][3] = (bt == 3) ? 1.f : 0.f;
    rinsh[s][4] = (bt == 4) ? 1.f : 0.f;
  }

  // rw2 columns for this thread's 2 outputs, resident in registers
  float2 w2[32];
  #pragma unroll
  for (int i = 0; i < 32; i++)
    w2[i] = *reinterpret_cast<const float2*>(rw2 + ((size_t)li*32 + i) * 512 + o0);
  const float2 rbv = *reinterpret_cast<const float2*>(rb2 + li * 512 + o0);

  const int ch = tid & 31;              // radial-hidden channel for precompute
  float w1r[5];
  #pragma unroll
  for (int i = 0; i < 5; i++) w1r[i] = rw1[(li*5 + i)*32 + ch];
  const float b1r = rb1[li*32 + ch];

  // int offset of first source node's nf row (fits 32-bit: nf = 7.3 MB)
  const int nfs0 = (b*64 + s0g) * 1792;

  float m_run = -1e30f, l_run = 0.0f;
  float acc0 = 0.0f, acc1 = 0.0f;

  __syncthreads();

  // ---- radial hidden (LN+relu) for this quarter's 16 edges ----
  #pragma unroll
  for (int p = 0; p < 2; p++) {
    const int e = p * 8 + (tid >> 5);
    float pre = b1r;
    #pragma unroll
    for (int i = 0; i < 5; i++) pre += rinsh[e][i] * w1r[i];
    float mu = pre;
    #pragma unroll
    for (int k = 16; k >= 1; k >>= 1) mu += __shfl_xor(mu, k, 32);
    mu *= 0.03125f;
    float dv = pre - mu;
    float var = dv * dv;
    #pragma unroll
    for (int k = 16; k >= 1; k >>= 1) var += __shfl_xor(var, k, 32);
    var *= 0.03125f;
    hmidAll[e][ch] = fmaxf(dv * rsqrtf(var + 1e-6f), 0.0f);
  }
  __syncthreads();

  for (int g = 0; g < 4; g++) {
    const int sb = g * 4;               // local source base
    const int buf = g & 1;

    // prefetch per-slot id_k (used in CD-a right after the barrier)
    float2 kid[4];
    #pragma unroll
    for (int e = 0; e < 4; e++)
      kid[e] = *reinterpret_cast<const float2*>(nf + nfs0 + (sb + e)*1792 + 256 + o0);

    // B: r = hmid @ rw2 + rb2 for 4 edges, this thread's 2 columns
    float2 racc[4];
    #pragma unroll
    for (int e = 0; e < 4; e++) racc[e] = rbv;
    #pragma unroll
    for (int e = 0; e < 4; e++) {
      const float4* hp = reinterpret_cast<const float4*>(&hmidAll[sb + e][0]);
      float rx = racc[e].x, ry = racc[e].y;
      #pragma unroll
      for (int i4 = 0; i4 < 8; i4++) {
        float4 h4 = hp[i4];
        float2 wa = w2[i4*4+0], wb = w2[i4*4+1], wc = w2[i4*4+2], wd = w2[i4*4+3];
        rx += h4.x*wa.x + h4.y*wb.x + h4.z*wc.x + h4.w*wd.x;
        ry += h4.x*wa.y + h4.y*wb.y + h4.z*wc.y + h4.w*wd.y;
      }
      racc[e].x = rx; racc[e].y = ry;
    }

    // Stage r4g: fold sck into path0, scv into path2
    #pragma unroll
    for (int e = 0; e < 4; e++) {
      float vx = racc[e].x, vy = racc[e].y;
      if (jj == 0) {
        const float2 sck = *reinterpret_cast<const float2*>(
            nf + nfs0 + (sb + e)*1792 + lw*32 + c0);
        vx *= sck.x; vy *= sck.y;
      } else if (jj == 2) {
        const float2 scv = *reinterpret_cast<const float2*>(
            nf + nfs0 + (sb + e)*1792 + 128 + lw*32 + c0);
        vx *= scv.x; vy *= scv.y;
      }
      float* rp = &r4g[buf][e*704];
      rp[c0*22 + lw*4 + jj]     = vx;
      rp[(c0+1)*22 + lw*4 + jj] = vy;
    }
    __syncthreads();

    // CD-a: per-slot k·q partial + butterfly over the 32-thread head group
    float lg[4];
    #pragma unroll
    for (int e = 0; e < 4; e++) {
      const float* rp = &r4g[buf][e*704];
      const float2 rAk = *reinterpret_cast<const float2*>(rp + oc*22 + l0*4);
      const float2 rBk = *reinterpret_cast<const float2*>(rp + oc*22 + l1*4);
      float pl = qv.x * (rAk.x * Ysh[sb+e][mg0] + rAk.y * kid[e].x)
               + qv.y * (rBk.x * Ysh[sb+e][mg1] + rBk.y * kid[e].y);
      pl += __shfl_xor(pl, 1, 32);
      pl += __shfl_xor(pl, 2, 32);
      pl += __shfl_xor(pl, 4, 32);
      pl += __shfl_xor(pl, 8, 32);
      pl += __shfl_xor(pl, 16, 32);
      lg[e] = (s0g + sb + e == d) ? -1e9f : pl * 0.125f;  // scale = 1/sqrt(hd*16)
    }

    // CD-b: online-softmax update of this thread's 2 o-slots
    {
      float m4 = fmaxf(fmaxf(lg[0], lg[1]), fmaxf(lg[2], lg[3]));
      float m_new = fmaxf(m_run, m4);
      float resc = __expf(m_run - m_new);
      acc0 *= resc; acc1 *= resc; l_run *= resc;
      #pragma unroll
      for (int e = 0; e < 4; e++) {
        float w = __expf(lg[e] - m_new);
        l_run += w;
        const float2 vid = *reinterpret_cast<const float2*>(
            nf + nfs0 + (sb + e)*1792 + 768 + o0);
        const float* rp = &r4g[buf][e*704];
        const float2 rAv = *reinterpret_cast<const float2*>(rp + oc*22 + l0*4 + 2);
        const float2 rBv = *reinterpret_cast<const float2*>(rp + oc*22 + l1*4 + 2);
        acc0 += w * (rAv.x * Ysh[sb+e][mg0] + rAv.y * vid.x);
        acc1 += w * (rBv.x * Ysh[sb+e][mg1] + rBv.y * vid.y);
      }
      m_run = m_new;
    }
  }

  // ---- emit partials (unnormalized) ----
  if ((tid & 31) == 0) {
    pml[(size_t)bx * 16 + ohh * 2]     = m_run;
    pml[(size_t)bx * 16 + ohh * 2 + 1] = l_run;
  }
  *reinterpret_cast<float2*>(pacc + (size_t)bx * 512 + o0) = make_float2(acc0, acc1);
}

// ------- combine partials + epilogue (Wself skip, NormSE3 gate) -------
__global__ __launch_bounds__(256) void combine_k(
    const float* __restrict__ f, const float* __restrict__ pml,
    const float* __restrict__ pacc, float* __restrict__ fnext,
    const float* __restrict__ Wself, const float* __restrict__ gnorm,
    const float* __restrict__ bnorm, int li) {
  __shared__ __align__(16) float fdst[512];
  __shared__ __align__(16) float osh[512];
  __shared__ float facsh[128];
  __shared__ float mls[4][16];

  const int bd = blockIdx.x;           // b*64 + d
  const int tid = threadIdx.x;
  const int o0 = 2 * tid;
  const int oc = tid >> 3;
  const int mg0 = 2 * (tid & 7), mg1 = mg0 + 1;
  const int l0 = lof(mg0), l1 = lof(mg1);
  const int ohh = oc >> 2;

  *reinterpret_cast<float2*>(fdst + o0) =
      *reinterpret_cast<const float2*>(f + (size_t)bd * 512 + o0);
  if (tid < 64) {
    int sp = tid >> 4, i = tid & 15;
    mls[sp][i] = pml[(size_t)(bd * 4 + sp) * 16 + i];
  }
  __syncthreads();

  float mstar = fmaxf(fmaxf(mls[0][ohh*2], mls[1][ohh*2]),
                      fmaxf(mls[2][ohh*2], mls[3][ohh*2]));
  float wsum = 0.f, a0 = 0.f, a1 = 0.f;
  #pragma unroll
  for (int sp = 0; sp < 4; sp++) {
    float ew = __expf(mls[sp][ohh*2] - mstar);
    wsum += mls[sp][ohh*2 + 1] * ew;
    const float2 pa = *reinterpret_cast<const float2*>(
        pacc + (size_t)(bd * 4 + sp) * 512 + o0);
    a0 += ew * pa.x;
    a1 += ew * pa.y;
  }
  const float invw = 1.0f / wsum;
  a0 *= invw; a1 *= invw;

  // Wself skip
  {
    const float* w0 = Wself + (size_t)((li*4 + l0)*32 + oc) * 32;
    const float* w1 = Wself + (size_t)((li*4 + l1)*32 + oc) * 32;
    #pragma unroll
    for (int i = 0; i < 32; i++) {
      a0 += w0[i] * fdst[i*16 + mg0];
      a1 += w1[i] * fdst[i*16 + mg1];
    }
  }
  osh[o0] = a0; osh[o0 + 1] = a1;
  __syncthreads();
  if (tid < 128) {
    const int c2 = tid >> 2, l2 = tid & 3;
    const int mb = mgb_of(l2), M2 = 2*l2 + 1;
    float ss = 0.f;
    for (int m = 0; m < M2; m++) { float v = osh[c2*16 + mb + m]; ss += v*v; }
    const float nrm = sqrtf(ss + 1e-6f);
    const float gg = gnorm[(li*4 + l2)*32 + c2];
    const float bb = bnorm[(li*4 + l2)*32 + c2];
    const float sg = fmaxf(gg*nrm + bb, 0.f);
    facsh[c2*4 + l2] = sg / nrm;
  }
  __syncthreads();
  *reinterpret_cast<float2*>(fnext + (size_t)bd * 512 + o0) =
      make_float2(a0 * facsh[oc*4 + l0], a1 * facsh[oc*4 + l1]);
}

// ---------------- readout: invariant norms -> mean over nodes -> Wfinal ----------------
__global__ __launch_bounds__(256) void readout_k(const float* __restrict__ f,
    const float* __restrict__ Wfinal, const float* __restrict__ bfinal,
    float* __restrict__ out) {
  __shared__ float invs[2][128];
  __shared__ float inv1[128];
  const int b = blockIdx.x;
  const int tid = threadIdx.x;
  const int j = tid & 127, half = tid >> 7;
  float p = 0.f;
  for (int n = half*32; n < half*32 + 32; n++) {
    const float* fn = f + (size_t)(b*64 + n) * 512;
    float v;
    if (j < 32) {
      v = fn[j*16];
    } else {
      int l = j >> 5, c = j & 31;
      int mb = mgb_of(l), M = 2*l + 1;
      float ss = 0.f;
      for (int m = 0; m < M; m++) { float t = fn[c*16 + mb + m]; ss += t*t; }
      v = sqrtf(ss + 1e-6f);
    }
    p += v;
  }
  invs[half][j] = p;
  __syncthreads();
  if (tid < 128) inv1[tid] = (invs[0][tid] + invs[1][tid]) * (1.0f / 64.0f);
  __syncthreads();
  if (tid < 128) {
    float acc = bfinal[tid];
    for (int k = 0; k < 128; k++) acc += inv1[k] * Wfinal[k*128 + tid];
    out[b*128 + tid] = acc;
  }
}

extern "C" void kernel_launch(void* const* d_in, const int* in_sizes, int n_in,
                              void* d_out, int out_size, void* d_ws, size_t ws_size,
                              hipStream_t stream) {
  (void)in_sizes; (void)n_in; (void)out_size; (void)ws_size;
  const float* h      = (const float*)d_in[0];
  const float* x      = (const float*)d_in[1];
  const int*   bond   = (const int*)d_in[2];
  const float* Wemb   = (const float*)d_in[3];
  const float* rw1    = (const float*)d_in[4];
  const float* rb1    = (const float*)d_in[5];
  const float* rw2    = (const float*)d_in[6];
  const float* rb2    = (const float*)d_in[7];
  const float* Wk     = (const float*)d_in[8];
  const float* Wv     = (const float*)d_in[9];
  const float* Wq     = (const float*)d_in[10];
  const float* Wself  = (const float*)d_in[11];
  const float* gnorm  = (const float*)d_in[12];
  const float* bnorm  = (const float*)d_in[13];
  const float* Wfinal = (const float*)d_in[14];
  const float* bfinal = (const float*)d_in[15];
  float* out = (float*)d_out;

  float* ws = (float*)d_ws;
  float* fA   = ws;                         // 524288 floats
  float* fB   = ws + 524288;                // 524288 floats
  float* nf   = ws + 2 * 524288;            // 1024*1792 = 1835008 floats
  float* pml  = ws + 2 * 524288 + 1835008;  // 4096*16 = 65536 floats
  float* pacc = pml + 65536;                // 4096*512 = 2097152 floats

  embed_k<<<2048, 256, 0, stream>>>(h, Wemb, fA);

  float* fc = fA; float* fn2 = fB;
  for (int li = 0; li < 4; li++) {
    nodefeats_k<<<1024, 256, 0, stream>>>(fc, Wk, Wv, Wq, nf, li);
    attn_k<<<4096, 256, 0, stream>>>(nf, pml, pacc, x, bond,
                                     rw1, rb1, rw2, rb2, li);
    combine_k<<<1024, 256, 0, stream>>>(fc, pml, pacc, fn2,
                                        Wself, gnorm, bnorm, li);
    float* t = fc; fc = fn2; fn2 = t;
  }

  readout_k<<<16, 256, 0, stream>>>(fc, Wfinal, bfinal, out);
}

// Round 6
// 520.608 us; speedup vs baseline: 3.4391x; 1.3034x over previous
//
#include <hip/hip_runtime.h>

// SE(3)-Transformer backbone, fp32, MI355X.
// Dims: B=16 N=64 FIN=16 C=32 D=4 (mg: l0=1, l1=3, l2=5, l3=7 -> 16) L=4 H=8 hd=4
// f layout: [b*64+n][c][mg] flat, 512 floats per node.
// nodefeats layout per node (1792 floats):
//   +0    sc_k[l*32+c]  (128)
//   +128  sc_v[l*32+c]  (128)
//   +256  id_k[c*16+mg] (512)
//   +768  id_v[c*16+mg] (512)
//   +1280 q   [c*16+mg] (512)
//
// Round-2 lesson: NO min-waves arg on __launch_bounds__ (spills w2 -> 1GB scratch).
// Round-3/5 lesson: barrier-synced wave gangs + few waves/SIMD = stall-bound
//   (VALUBusy 36%, occ 21%). Round 6: head-split waves — each wave owns 2 heads
//   (128 slots + exactly the 128 r-columns they consume), walks all 64 sources
//   independently, zero barriers in the main loop; combine kernel deleted.

__device__ __forceinline__ int lof(int mg)   { return (mg==0)?0:((mg<4)?1:((mg<9)?2:3)); }
__device__ __forceinline__ int mgb_of(int l) { return (l==0)?0:((l==1)?1:((l==2)?4:9)); }

// ---------------- embed: f0 = h @ Wemb, higher degrees zero ----------------
__global__ __launch_bounds__(256) void embed_k(const float* __restrict__ h,
                                               const float* __restrict__ Wemb,
                                               float* __restrict__ f) {
  int idx = blockIdx.x * 256 + threadIdx.x;   // covers 16*64*512 = 524288
  int node = idx >> 9;
  int rem  = idx & 511;
  int c = rem >> 4, mg = rem & 15;
  float v = 0.f;
  if (mg == 0) {
    const float* hh = h + node * 16;
    #pragma unroll
    for (int i = 0; i < 16; i++) v += hh[i] * Wemb[i * 32 + c];
  }
  f[idx] = v;
}

// ---------------- per-node K/V/Q projections ----------------
__global__ __launch_bounds__(256) void nodefeats_k(const float* __restrict__ f,
    const float* __restrict__ Wk, const float* __restrict__ Wv,
    const float* __restrict__ Wq, float* __restrict__ nf, int li) {
  __shared__ __align__(16) float fl[512];
  const int node = blockIdx.x;
  const int tid = threadIdx.x;
  reinterpret_cast<float2*>(fl)[tid] =
      reinterpret_cast<const float2*>(f + (size_t)node * 512)[tid];
  __syncthreads();
  float* out = nf + (size_t)node * 1792;
  #pragma unroll
  for (int k = 0; k < 7; k++) {
    int o = tid + k * 256;
    float acc = 0.f;
    if (o < 128) {                       // sc_k
      int l = o >> 5, c = o & 31;
      const float* w = Wk + (size_t)(((li*4 + l)*2 + 0)*32 + c) * 32;
      #pragma unroll
      for (int i = 0; i < 32; i++) acc += w[i] * fl[i*16];
    } else if (o < 256) {                // sc_v
      int o2 = o - 128; int l = o2 >> 5, c = o2 & 31;
      const float* w = Wv + (size_t)(((li*4 + l)*2 + 0)*32 + c) * 32;
      #pragma unroll
      for (int i = 0; i < 32; i++) acc += w[i] * fl[i*16];
    } else if (o < 768) {                // id_k
      int o2 = o - 256; int c = o2 >> 4, mg = o2 & 15, l = lof(mg);
      const float* w = Wk + (size_t)(((li*4 + l)*2 + 1)*32 + c) * 32;
      #pragma unroll
      for (int i = 0; i < 32; i++) acc += w[i] * fl[i*16 + mg];
    } else if (o < 1280) {               // id_v
      int o2 = o - 768; int c = o2 >> 4, mg = o2 & 15, l = lof(mg);
      const float* w = Wv + (size_t)(((li*4 + l)*2 + 1)*32 + c) * 32;
      #pragma unroll
      for (int i = 0; i < 32; i++) acc += w[i] * fl[i*16 + mg];
    } else {                             // q
      int o2 = o - 1280; int c = o2 >> 4, mg = o2 & 15, l = lof(mg);
      const float* w = Wq + (size_t)((li*4 + l)*32 + c) * 32;
      #pragma unroll
      for (int i = 0; i < 32; i++) acc += w[i] * fl[i*16 + mg];
    }
    out[o] = acc;
  }
}

// -------- fused attention layer: one block per (b,dst); one WAVE per 2 heads --------
// Wave w owns output slots 128w..128w+127 (heads 2w,2w+1) AND computes exactly the
// 128 r-columns (l, path, c in its channels) those slots consume. No barriers in the
// source loop; waves proceed independently. Epilogue (Wself + NormSE3) fused.
__global__ __launch_bounds__(256) void attn_k(
    const float* __restrict__ f, const float* __restrict__ nf,
    float* __restrict__ fnext,
    const float* __restrict__ x, const int* __restrict__ bond,
    const float* __restrict__ rw1, const float* __restrict__ rb1,
    const float* __restrict__ rw2, const float* __restrict__ rb2,
    const float* __restrict__ Wself, const float* __restrict__ gnorm,
    const float* __restrict__ bnorm, int li) {
  __shared__ __align__(16) float Ysh[64][16];     // Y per source; reused as osh in epilogue
  __shared__ float rinsh[64][8];                  // dist+bond one-hots; reused as facsh
  __shared__ __align__(16) float hmidAll[64][32]; // radial hidden, all 64 edges
  __shared__ __align__(16) float fdst[512];       // dst fiber (Wself skip)
  __shared__ __align__(16) float rst[4][128];     // wave-private r staging [ccl*16 + l*4 + p]

  const int tid = threadIdx.x;
  const int bd  = blockIdx.x;          // b*64 + d
  const int b = bd >> 6, d = bd & 63;
  const int w = tid >> 6;              // wave id: heads 2w, 2w+1
  const int t = tid & 63;              // lane

  // output-slot decode (2 slots per lane)
  const int slot0 = 128*w + 2*t;
  const int oc  = slot0 >> 4;          // channel (8w .. 8w+7)
  const int mg0 = slot0 & 15, mg1 = mg0 + 1;
  const int l0 = lof(mg0), l1 = lof(mg1);

  // r-column assignment: col = lc*128 + pc*32 + cc0 (+1)
  const int lc  = t >> 4;              // degree of this lane's columns
  const int pc  = (t >> 2) & 3;        // radial path of this lane's columns
  const int ccl = 2 * (t & 3);         // local channel (even)
  const int cc0 = 8*w + ccl;           // global channel

  // ---- prologue loads ----
  const int o0 = 2 * tid;
  *reinterpret_cast<float2*>(fdst + o0) =
      *reinterpret_cast<const float2*>(f + (size_t)bd * 512 + o0);
  const float2 qv = *reinterpret_cast<const float2*>(
      nf + (size_t)bd * 1792 + 1280 + slot0);

  if (tid < 64) {               // geometry for source s = tid
    const int s = tid;
    const float* xb = x + (size_t)b * 192;
    float xd = xb[d*3+0], yd = xb[d*3+1], zd = xb[d*3+2];
    float dx = xb[s*3+0] - xd, dy = xb[s*3+1] - yd, dz = xb[s*3+2] - zd;
    float dist = sqrtf(dx*dx + dy*dy + dz*dz + 1e-6f);
    float inv = 1.0f / dist;
    float xx = dx*inv, yy = dy*inv, zz = dz*inv;
    float* Y = Ysh[s];
    Y[0]  = 0.28209479177387814f;
    Y[1]  = 0.4886025119029199f * yy;
    Y[2]  = 0.4886025119029199f * zz;
    Y[3]  = 0.4886025119029199f * xx;
    Y[4]  = 1.0925484305920792f * xx * yy;
    Y[5]  = 1.0925484305920792f * yy * zz;
    Y[6]  = 0.31539156525252005f * (3.0f*zz*zz - 1.0f);
    Y[7]  = 1.0925484305920792f * xx * zz;
    Y[8]  = 0.5462742152960396f * (xx*xx - yy*yy);
    Y[9]  = 0.5900435899266435f * yy * (3.0f*xx*xx - yy*yy);
    Y[10] = 2.890611442640554f  * xx * yy * zz;
    Y[11] = 0.4570457994644658f * yy * (5.0f*zz*zz - 1.0f);
    Y[12] = 0.3731763325901154f * zz * (5.0f*zz*zz - 3.0f);
    Y[13] = 0.4570457994644658f * xx * (5.0f*zz*zz - 1.0f);
    Y[14] = 1.445305721320277f  * zz * (xx*xx - yy*yy);
    Y[15] = 0.5900435899266435f * xx * (xx*xx - yy*yy);
    rinsh[s][0] = dist;
    int bt = bond[(size_t)b * 4096 + d * 64 + s];
    bt = bt < 0 ? 0 : (bt > 4 ? 4 : bt);
    rinsh[s][1] = (bt == 1) ? 1.f : 0.f;
    rinsh[s][2] = (bt == 2) ? 1.f : 0.f;
    rinsh[s][3] = (bt == 3) ? 1.f : 0.f;
    rinsh[s][4] = (bt == 4) ? 1.f : 0.f;
  }

  // rw2 columns for this lane's 2 r-columns, register-resident
  float2 w2[32];
  {
    const float* wp = rw2 + (size_t)li*32*512 + lc*128 + pc*32 + cc0;
    #pragma unroll
    for (int i = 0; i < 32; i++)
      w2[i] = *reinterpret_cast<const float2*>(wp + i*512);
  }
  const float2 rbv = *reinterpret_cast<const float2*>(
      rb2 + li*512 + lc*128 + pc*32 + cc0);

  const int ch = tid & 31;
  float w1r[5];
  #pragma unroll
  for (int i = 0; i < 5; i++) w1r[i] = rw1[(li*5 + i)*32 + ch];
  const float b1r = rb1[li*32 + ch];

  __syncthreads();

  // ---- radial hidden (LN+relu) for all 64 edges ----
  #pragma unroll
  for (int p = 0; p < 8; p++) {
    const int e = p * 8 + (tid >> 5);
    float pre = b1r;
    #pragma unroll
    for (int i = 0; i < 5; i++) pre += rinsh[e][i] * w1r[i];
    float mu = pre;
    #pragma unroll
    for (int k = 16; k >= 1; k >>= 1) mu += __shfl_xor(mu, k, 32);
    mu *= 0.03125f;
    float dv = pre - mu;
    float var = dv * dv;
    #pragma unroll
    for (int k = 16; k >= 1; k >>= 1) var += __shfl_xor(var, k, 32);
    var *= 0.03125f;
    hmidAll[e][ch] = fmaxf(dv * rsqrtf(var + 1e-6f), 0.0f);
  }
  __syncthreads();
  // From here: Ysh/hmidAll/fdst are read-only; waves run fully independently.

  // per-edge operand offsets (nf fits 32-bit int offsets)
  const int nfb   = (b * 64) * 1792;
  const int offK  = 256 + slot0;                       // id_k per-slot
  const int offV  = 768 + slot0;                       // id_v per-slot
  const int offSC = ((pc & 2) << 6) + lc*32 + cc0;     // sc_k (p0/p1) or sc_v (p2/p3)
  const int wr0 = ccl*16 + lc*4 + pc;                  // staging write idx
  const int rdA = (t >> 3)*16 + l0*4;                  // staging read idx (float4)
  const int rdB = (t >> 3)*16 + l1*4;
  const bool foldsc = (pc & 1) == 0;
  float* rstw = &rst[w][0];

  float m_run = -1e30f, l_run = 0.0f;
  float acc0 = 0.0f, acc1 = 0.0f;

  // preload edge-0 operands
  float2 kidc = *reinterpret_cast<const float2*>(nf + nfb + offK);
  float2 vidc = *reinterpret_cast<const float2*>(nf + nfb + offV);
  float2 scc  = *reinterpret_cast<const float2*>(nf + nfb + offSC);

  for (int e = 0; e < 64; e++) {
    // prefetch next edge's operands (hide under the FMA block)
    float2 kidn = kidc, vidn = vidc, scn = scc;
    if (e < 63) {
      const float* np = nf + nfb + (e + 1) * 1792;
      kidn = *reinterpret_cast<const float2*>(np + offK);
      vidn = *reinterpret_cast<const float2*>(np + offV);
      scn  = *reinterpret_cast<const float2*>(np + offSC);
    }

    // B: this lane's 2 r-columns for edge e
    float rx = rbv.x, ry = rbv.y;
    {
      const float4* hp = reinterpret_cast<const float4*>(&hmidAll[e][0]);
      #pragma unroll
      for (int i4 = 0; i4 < 8; i4++) {
        float4 h4 = hp[i4];
        float2 wa = w2[i4*4+0], wb = w2[i4*4+1], wc = w2[i4*4+2], wd = w2[i4*4+3];
        rx += h4.x*wa.x + h4.y*wb.x + h4.z*wc.x + h4.w*wd.x;
        ry += h4.x*wa.y + h4.y*wb.y + h4.z*wc.y + h4.w*wd.y;
      }
    }
    // fold sc_k / sc_v into paths 0 / 2
    rx *= foldsc ? scc.x : 1.0f;
    ry *= foldsc ? scc.y : 1.0f;

    // wave-private stage + same-wave readback (no block barrier)
    rstw[wr0]      = rx;
    rstw[wr0 + 16] = ry;
    asm volatile("s_waitcnt lgkmcnt(0)" ::: "memory");
    const float4 rA = *reinterpret_cast<const float4*>(rstw + rdA);
    const float4 rB = *reinterpret_cast<const float4*>(rstw + rdB);

    const float ym0 = Ysh[e][mg0], ym1 = Ysh[e][mg1];

    // logit: k·q partial over this lane's 2 slots, butterfly over 32-lane head group
    float pl = qv.x * (rA.x * ym0 + rA.y * kidc.x)
             + qv.y * (rB.x * ym1 + rB.y * kidc.y);
    pl += __shfl_xor(pl, 1);
    pl += __shfl_xor(pl, 2);
    pl += __shfl_xor(pl, 4);
    pl += __shfl_xor(pl, 8);
    pl += __shfl_xor(pl, 16);
    const float lg = (e == d) ? -1e9f : pl * 0.125f;   // scale = 1/sqrt(hd*16)

    // online softmax update
    const float m_new = fmaxf(m_run, lg);
    const float resc  = __expf(m_run - m_new);
    const float wgt   = __expf(lg - m_new);
    acc0 = acc0 * resc + wgt * (rA.z * ym0 + rA.w * vidc.x);
    acc1 = acc1 * resc + wgt * (rB.z * ym1 + rB.w * vidc.y);
    l_run = l_run * resc + wgt;
    m_run = m_new;

    kidc = kidn; vidc = vidn; scc = scn;
  }

  // ---- epilogue: normalize, Wself skip, NormSE3 gate, write ----
  const float invl = 1.0f / l_run;
  acc0 *= invl; acc1 *= invl;
  {
    const float* w0 = Wself + (size_t)((li*4 + l0)*32 + oc) * 32;
    const float* w1 = Wself + (size_t)((li*4 + l1)*32 + oc) * 32;
    #pragma unroll
    for (int i = 0; i < 32; i++) {
      acc0 += w0[i] * fdst[i*16 + mg0];
      acc1 += w1[i] * fdst[i*16 + mg1];
    }
  }
  __syncthreads();                     // all waves done reading Ysh
  float* osh = &Ysh[0][0];             // reuse
  osh[slot0] = acc0; osh[slot0 + 1] = acc1;
  __syncthreads();
  float* facsh = &rinsh[0][0];         // reuse
  if (tid < 128) {
    const int c2 = tid >> 2, l2 = tid & 3;
    const int mb = mgb_of(l2), M2 = 2*l2 + 1;
    float ss = 0.f;
    for (int m = 0; m < M2; m++) { float v = osh[c2*16 + mb + m]; ss += v*v; }
    const float nrm = sqrtf(ss + 1e-6f);
    const float gg = gnorm[(li*4 + l2)*32 + c2];
    const float bb = bnorm[(li*4 + l2)*32 + c2];
    const float sg = fmaxf(gg*nrm + bb, 0.f);
    facsh[c2*4 + l2] = sg / nrm;
  }
  __syncthreads();
  *reinterpret_cast<float2*>(fnext + (size_t)bd * 512 + slot0) =
      make_float2(acc0 * facsh[oc*4 + l0], acc1 * facsh[oc*4 + l1]);
}

// ---------------- readout: invariant norms -> mean over nodes -> Wfinal ----------------
__global__ __launch_bounds__(256) void readout_k(const float* __restrict__ f,
    const float* __restrict__ Wfinal, const float* __restrict__ bfinal,
    float* __restrict__ out) {
  __shared__ float invs[2][128];
  __shared__ float inv1[128];
  const int b = blockIdx.x;
  const int tid = threadIdx.x;
  const int j = tid & 127, half = tid >> 7;
  float p = 0.f;
  for (int n = half*32; n < half*32 + 32; n++) {
    const float* fn = f + (size_t)(b*64 + n) * 512;
    float v;
    if (j < 32) {
      v = fn[j*16];
    } else {
      int l = j >> 5, c = j & 31;
      int mb = mgb_of(l), M = 2*l + 1;
      float ss = 0.f;
      for (int m = 0; m < M; m++) { float t = fn[c*16 + mb + m]; ss += t*t; }
      v = sqrtf(ss + 1e-6f);
    }
    p += v;
  }
  invs[half][j] = p;
  __syncthreads();
  if (tid < 128) inv1[tid] = (invs[0][tid] + invs[1][tid]) * (1.0f / 64.0f);
  __syncthreads();
  if (tid < 128) {
    float acc = bfinal[tid];
    for (int k = 0; k < 128; k++) acc += inv1[k] * Wfinal[k*128 + tid];
    out[b*128 + tid] = acc;
  }
}

extern "C" void kernel_launch(void* const* d_in, const int* in_sizes, int n_in,
                              void* d_out, int out_size, void* d_ws, size_t ws_size,
                              hipStream_t stream) {
  (void)in_sizes; (void)n_in; (void)out_size; (void)ws_size;
  const float* h      = (const float*)d_in[0];
  const float* x      = (const float*)d_in[1];
  const int*   bond   = (const int*)d_in[2];
  const float* Wemb   = (const float*)d_in[3];
  const float* rw1    = (const float*)d_in[4];
  const float* rb1    = (const float*)d_in[5];
  const float* rw2    = (const float*)d_in[6];
  const float* rb2    = (const float*)d_in[7];
  const float* Wk     = (const float*)d_in[8];
  const float* Wv     = (const float*)d_in[9];
  const float* Wq     = (const float*)d_in[10];
  const float* Wself  = (const float*)d_in[11];
  const float* gnorm  = (const float*)d_in[12];
  const float* bnorm  = (const float*)d_in[13];
  const float* Wfinal = (const float*)d_in[14];
  const float* bfinal = (const float*)d_in[15];
  float* out = (float*)d_out;

  float* ws = (float*)d_ws;
  float* fA = ws;                       // 524288 floats
  float* fB = ws + 524288;              // 524288 floats
  float* nf = ws + 2 * 524288;          // 1024*1792 floats

  embed_k<<<2048, 256, 0, stream>>>(h, Wemb, fA);

  float* fc = fA; float* fn2 = fB;
  for (int li = 0; li < 4; li++) {
    nodefeats_k<<<1024, 256, 0, stream>>>(fc, Wk, Wv, Wq, nf, li);
    attn_k<<<1024, 256, 0, stream>>>(fc, nf, fn2, x, bond,
                                     rw1, rb1, rw2, rb2, Wself, gnorm, bnorm, li);
    float* t = fc; fc = fn2; fn2 = t;
  }

  readout_k<<<16, 256, 0, stream>>>(fc, Wfinal, bfinal, out);
}

// Round 7
// 497.571 us; speedup vs baseline: 3.5983x; 1.0463x over previous
//
#include <hip/hip_runtime.h>

// SE(3)-Transformer backbone, fp32, MI355X.
// Dims: B=16 N=64 FIN=16 C=32 D=4 (mg: l0=1, l1=3, l2=5, l3=7 -> 16) L=4 H=8 hd=4
// f layout: [b*64+n][c][mg] flat, 512 floats per node.
// nodefeats layout per node (1792 floats):
//   +0    sc_k[l*32+c]  (128)
//   +128  sc_v[l*32+c]  (128)
//   +256  id_k[c*16+mg] (512)
//   +768  id_v[c*16+mg] (512)
//   +1280 q   [c*16+mg] (512)
//
// Round-2 lesson: NO min-waves arg on __launch_bounds__ (spill disaster).
// Round-6 lesson: VGPR=76 proves compiler rematerialized w2[] from global inside
//   the edge loop (should be ~110 live). Round 7: 4-edge groups + asm anchor to
//   pin w2 in VGPRs; nodefeats fused into attn epilogue (nf double-buffered);
//   embed+nodefeats0 fused into prep_k. 10 -> 6 launches.

__device__ __forceinline__ int lof(int mg)   { return (mg==0)?0:((mg<4)?1:((mg<9)?2:3)); }
__device__ __forceinline__ int mgb_of(int l) { return (l==0)?0:((l==1)?1:((l==2)?4:9)); }

// ---- shared nodefeats projection: fl = node fiber (512, LDS), out = nf row ----
__device__ __forceinline__ void nf_project(const float* fl, float* out,
    const float* __restrict__ Wk, const float* __restrict__ Wv,
    const float* __restrict__ Wq, int li, int tid) {
  #pragma unroll
  for (int k = 0; k < 7; k++) {
    int o = tid + k * 256;
    float acc = 0.f;
    if (o < 128) {                       // sc_k
      int l = o >> 5, c = o & 31;
      const float* w = Wk + (size_t)(((li*4 + l)*2 + 0)*32 + c) * 32;
      #pragma unroll
      for (int i = 0; i < 32; i++) acc += w[i] * fl[i*16];
    } else if (o < 256) {                // sc_v
      int o2 = o - 128; int l = o2 >> 5, c = o2 & 31;
      const float* w = Wv + (size_t)(((li*4 + l)*2 + 0)*32 + c) * 32;
      #pragma unroll
      for (int i = 0; i < 32; i++) acc += w[i] * fl[i*16];
    } else if (o < 768) {                // id_k
      int o2 = o - 256; int c = o2 >> 4, mg = o2 & 15, l = lof(mg);
      const float* w = Wk + (size_t)(((li*4 + l)*2 + 1)*32 + c) * 32;
      #pragma unroll
      for (int i = 0; i < 32; i++) acc += w[i] * fl[i*16 + mg];
    } else if (o < 1280) {               // id_v
      int o2 = o - 768; int c = o2 >> 4, mg = o2 & 15, l = lof(mg);
      const float* w = Wv + (size_t)(((li*4 + l)*2 + 1)*32 + c) * 32;
      #pragma unroll
      for (int i = 0; i < 32; i++) acc += w[i] * fl[i*16 + mg];
    } else {                             // q
      int o2 = o - 1280; int c = o2 >> 4, mg = o2 & 15, l = lof(mg);
      const float* w = Wq + (size_t)((li*4 + l)*32 + c) * 32;
      #pragma unroll
      for (int i = 0; i < 32; i++) acc += w[i] * fl[i*16 + mg];
    }
    out[o] = acc;
  }
}

// ---------------- prep: embed (f0 = h @ Wemb) + nodefeats for layer 0 ----------------
__global__ __launch_bounds__(256) void prep_k(const float* __restrict__ h,
    const float* __restrict__ Wemb,
    const float* __restrict__ Wk, const float* __restrict__ Wv,
    const float* __restrict__ Wq,
    float* __restrict__ f, float* __restrict__ nf) {
  __shared__ __align__(16) float fl[512];
  const int node = blockIdx.x;
  const int tid = threadIdx.x;
  fl[2*tid] = 0.f; fl[2*tid + 1] = 0.f;
  __syncthreads();
  if (tid < 32) {
    const float* hh = h + node * 16;
    float v = 0.f;
    #pragma unroll
    for (int i = 0; i < 16; i++) v += hh[i] * Wemb[i * 32 + tid];
    fl[tid * 16] = v;
  }
  __syncthreads();
  *reinterpret_cast<float2*>(f + (size_t)node * 512 + 2*tid) =
      *reinterpret_cast<const float2*>(fl + 2*tid);
  nf_project(fl, nf + (size_t)node * 1792, Wk, Wv, Wq, 0, tid);
}

// -------- fused attention layer: one block per (b,dst); one WAVE per 2 heads --------
// 4-edge groups; no barriers in the source loop; epilogue = Wself + NormSE3 +
// next-layer nodefeats (written to nf_out, double-buffered by caller).
__global__ __launch_bounds__(256) void attn_k(
    const float* __restrict__ f, const float* __restrict__ nf,
    float* __restrict__ fnext,
    const float* __restrict__ x, const int* __restrict__ bond,
    const float* __restrict__ rw1, const float* __restrict__ rb1,
    const float* __restrict__ rw2, const float* __restrict__ rb2,
    const float* __restrict__ Wself, const float* __restrict__ gnorm,
    const float* __restrict__ bnorm,
    const float* __restrict__ Wk, const float* __restrict__ Wv,
    const float* __restrict__ Wq,
    float* __restrict__ nf_out, int li) {
  __shared__ __align__(16) float Ysh[64][16];     // Y per source; reused as osh in epilogue
  __shared__ float rinsh[64][8];                  // dist+bond one-hots; reused as facsh
  __shared__ __align__(16) float hmidAll[64][32]; // radial hidden, all 64 edges
  __shared__ __align__(16) float fdst[512];       // dst fiber (Wself skip)
  __shared__ __align__(16) float rst[4][4][128];  // wave-private r staging [wave][edge][c*16+l*4+p]

  const int tid = threadIdx.x;
  const int bd  = blockIdx.x;          // b*64 + d
  const int b = bd >> 6, d = bd & 63;
  const int wv = tid >> 6;             // wave id: heads 2wv, 2wv+1
  const int t = tid & 63;              // lane

  // output-slot decode (2 slots per lane)
  const int slot0 = 128*wv + 2*t;
  const int oc  = slot0 >> 4;          // channel (8wv .. 8wv+7)
  const int mg0 = slot0 & 15, mg1 = mg0 + 1;
  const int l0 = lof(mg0), l1 = lof(mg1);

  // r-column assignment: col = lc*128 + pc*32 + cc0 (+1)
  const int lc  = t >> 4;              // degree of this lane's columns
  const int pc  = (t >> 2) & 3;        // radial path of this lane's columns
  const int ccl = 2 * (t & 3);         // local channel (even)
  const int cc0 = 8*wv + ccl;          // global channel

  // ---- prologue loads ----
  const int o0 = 2 * tid;
  *reinterpret_cast<float2*>(fdst + o0) =
      *reinterpret_cast<const float2*>(f + (size_t)bd * 512 + o0);
  const float2 qv = *reinterpret_cast<const float2*>(
      nf + (size_t)bd * 1792 + 1280 + slot0);

  if (tid < 64) {               // geometry for source s = tid
    const int s = tid;
    const float* xb = x + (size_t)b * 192;
    float xd = xb[d*3+0], yd = xb[d*3+1], zd = xb[d*3+2];
    float dx = xb[s*3+0] - xd, dy = xb[s*3+1] - yd, dz = xb[s*3+2] - zd;
    float dist = sqrtf(dx*dx + dy*dy + dz*dz + 1e-6f);
    float inv = 1.0f / dist;
    float xx = dx*inv, yy = dy*inv, zz = dz*inv;
    float* Y = Ysh[s];
    Y[0]  = 0.28209479177387814f;
    Y[1]  = 0.4886025119029199f * yy;
    Y[2]  = 0.4886025119029199f * zz;
    Y[3]  = 0.4886025119029199f * xx;
    Y[4]  = 1.0925484305920792f * xx * yy;
    Y[5]  = 1.0925484305920792f * yy * zz;
    Y[6]  = 0.31539156525252005f * (3.0f*zz*zz - 1.0f);
    Y[7]  = 1.0925484305920792f * xx * zz;
    Y[8]  = 0.5462742152960396f * (xx*xx - yy*yy);
    Y[9]  = 0.5900435899266435f * yy * (3.0f*xx*xx - yy*yy);
    Y[10] = 2.890611442640554f  * xx * yy * zz;
    Y[11] = 0.4570457994644658f * yy * (5.0f*zz*zz - 1.0f);
    Y[12] = 0.3731763325901154f * zz * (5.0f*zz*zz - 3.0f);
    Y[13] = 0.4570457994644658f * xx * (5.0f*zz*zz - 1.0f);
    Y[14] = 1.445305721320277f  * zz * (xx*xx - yy*yy);
    Y[15] = 0.5900435899266435f * xx * (xx*xx - yy*yy);
    rinsh[s][0] = dist;
    int bt = bond[(size_t)b * 4096 + d * 64 + s];
    bt = bt < 0 ? 0 : (bt > 4 ? 4 : bt);
    rinsh[s][1] = (bt == 1) ? 1.f : 0.f;
    rinsh[s][2] = (bt == 2) ? 1.f : 0.f;
    rinsh[s][3] = (bt == 3) ? 1.f : 0.f;
    rinsh[s][4] = (bt == 4) ? 1.f : 0.f;
  }

  // rw2 columns for this lane's 2 r-columns; asm anchor pins them in VGPRs
  float2 w2[32];
  {
    const float* wp = rw2 + (size_t)li*32*512 + lc*128 + pc*32 + cc0;
    #pragma unroll
    for (int i = 0; i < 32; i++)
      w2[i] = *reinterpret_cast<const float2*>(wp + i*512);
  }
  #pragma unroll
  for (int i = 0; i < 32; i++)
    asm volatile("" : "+v"(w2[i].x), "+v"(w2[i].y));   // forbid rematerialization
  const float2 rbv = *reinterpret_cast<const float2*>(
      rb2 + li*512 + lc*128 + pc*32 + cc0);

  const int ch = tid & 31;
  float w1r[5];
  #pragma unroll
  for (int i = 0; i < 5; i++) w1r[i] = rw1[(li*5 + i)*32 + ch];
  const float b1r = rb1[li*32 + ch];

  __syncthreads();

  // ---- radial hidden (LN+relu) for all 64 edges ----
  #pragma unroll
  for (int p = 0; p < 8; p++) {
    const int e = p * 8 + (tid >> 5);
    float pre = b1r;
    #pragma unroll
    for (int i = 0; i < 5; i++) pre += rinsh[e][i] * w1r[i];
    float mu = pre;
    #pragma unroll
    for (int k = 16; k >= 1; k >>= 1) mu += __shfl_xor(mu, k, 32);
    mu *= 0.03125f;
    float dv = pre - mu;
    float var = dv * dv;
    #pragma unroll
    for (int k = 16; k >= 1; k >>= 1) var += __shfl_xor(var, k, 32);
    var *= 0.03125f;
    hmidAll[e][ch] = fmaxf(dv * rsqrtf(var + 1e-6f), 0.0f);
  }
  __syncthreads();
  // From here: Ysh/hmidAll/fdst read-only; waves run fully independently.

  const int nfb   = (b * 64) * 1792;
  const int offK  = 256 + slot0;                       // id_k per-slot
  const int offV  = 768 + slot0;                       // id_v per-slot
  const int offSC = ((pc & 2) << 6) + lc*32 + cc0;     // sc_k (p0/p1) / sc_v (p2/p3)
  const int wr0 = ccl*16 + lc*4 + pc;                  // staging write idx
  const int rdA = (t >> 3)*16 + l0*4;                  // staging read idx (float4)
  const int rdB = (t >> 3)*16 + l1*4;
  const bool foldsc = (pc & 1) == 0;
  float* rstw = &rst[wv][0][0];

  float m_run = -1e30f, l_run = 0.0f;
  float acc0 = 0.0f, acc1 = 0.0f;

  for (int g = 0; g < 16; g++) {
    const int e0 = g * 4;
    // operand batch for 4 edges (loads issue up front; B-step FMAs cover latency)
    float2 kid[4], vid[4], scg[4];
    #pragma unroll
    for (int e = 0; e < 4; e++) {
      const float* np = nf + nfb + (e0 + e) * 1792;
      kid[e] = *reinterpret_cast<const float2*>(np + offK);
      vid[e] = *reinterpret_cast<const float2*>(np + offV);
      scg[e] = *reinterpret_cast<const float2*>(np + offSC);
    }

    // B: this lane's 2 r-columns for 4 edges (16 independent FMA chains)
    #pragma unroll
    for (int e = 0; e < 4; e++) {
      const float4* hp = reinterpret_cast<const float4*>(&hmidAll[e0 + e][0]);
      float rx0 = rbv.x, rx1 = 0.f, ry0 = rbv.y, ry1 = 0.f;
      #pragma unroll
      for (int i4 = 0; i4 < 8; i4 += 2) {
        float4 ha = hp[i4], hb = hp[i4 + 1];
        float2 wa = w2[i4*4+0], wb = w2[i4*4+1], wc = w2[i4*4+2], wd = w2[i4*4+3];
        float2 we = w2[i4*4+4], wf = w2[i4*4+5], wg = w2[i4*4+6], wh = w2[i4*4+7];
        rx0 += ha.x*wa.x + ha.y*wb.x + ha.z*wc.x + ha.w*wd.x;
        ry0 += ha.x*wa.y + ha.y*wb.y + ha.z*wc.y + ha.w*wd.y;
        rx1 += hb.x*we.x + hb.y*wf.x + hb.z*wg.x + hb.w*wh.x;
        ry1 += hb.x*we.y + hb.y*wf.y + hb.z*wg.y + hb.w*wh.y;
      }
      float rx = rx0 + rx1, ry = ry0 + ry1;
      if (foldsc) { rx *= scg[e].x; ry *= scg[e].y; }
      rstw[e*128 + wr0]      = rx;
      rstw[e*128 + wr0 + 16] = ry;
    }
    asm volatile("s_waitcnt lgkmcnt(0)" ::: "memory");

    // consume: logits (independent across edges) then softmax chain
    float lg[4], vA[4], vB[4];
    #pragma unroll
    for (int e = 0; e < 4; e++) {
      const float* rp = rstw + e*128;
      const float4 rA = *reinterpret_cast<const float4*>(rp + rdA);
      const float4 rB = *reinterpret_cast<const float4*>(rp + rdB);
      const float ym0 = Ysh[e0 + e][mg0], ym1 = Ysh[e0 + e][mg1];
      float pl = qv.x * (rA.x * ym0 + rA.y * kid[e].x)
               + qv.y * (rB.x * ym1 + rB.y * kid[e].y);
      pl += __shfl_xor(pl, 1);
      pl += __shfl_xor(pl, 2);
      pl += __shfl_xor(pl, 4);
      pl += __shfl_xor(pl, 8);
      pl += __shfl_xor(pl, 16);
      lg[e] = (e0 + e == d) ? -1e9f : pl * 0.125f;   // scale = 1/sqrt(hd*16)
      vA[e] = rA.z * ym0 + rA.w * vid[e].x;
      vB[e] = rB.z * ym1 + rB.w * vid[e].y;
    }
    {
      const float m4 = fmaxf(fmaxf(lg[0], lg[1]), fmaxf(lg[2], lg[3]));
      const float m_new = fmaxf(m_run, m4);
      const float resc = __expf(m_run - m_new);
      acc0 *= resc; acc1 *= resc; l_run *= resc;
      #pragma unroll
      for (int e = 0; e < 4; e++) {
        const float wgt = __expf(lg[e] - m_new);
        l_run += wgt;
        acc0 += wgt * vA[e];
        acc1 += wgt * vB[e];
      }
      m_run = m_new;
    }
  }

  // ---- epilogue: normalize, Wself skip, NormSE3 gate, write, next-layer nf ----
  const float invl = 1.0f / l_run;
  acc0 *= invl; acc1 *= invl;
  {
    const float* w0 = Wself + (size_t)((li*4 + l0)*32 + oc) * 32;
    const float* w1 = Wself + (size_t)((li*4 + l1)*32 + oc) * 32;
    #pragma unroll
    for (int i = 0; i < 32; i++) {
      acc0 += w0[i] * fdst[i*16 + mg0];
      acc1 += w1[i] * fdst[i*16 + mg1];
    }
  }
  __syncthreads();                     // all waves done reading Ysh
  float* osh = &Ysh[0][0];             // reuse
  osh[slot0] = acc0; osh[slot0 + 1] = acc1;
  __syncthreads();
  float* facsh = &rinsh[0][0];         // reuse
  if (tid < 128) {
    const int c2 = tid >> 2, l2 = tid & 3;
    const int mb = mgb_of(l2), M2 = 2*l2 + 1;
    float ss = 0.f;
    for (int m = 0; m < M2; m++) { float v = osh[c2*16 + mb + m]; ss += v*v; }
    const float nrm = sqrtf(ss + 1e-6f);
    const float gg = gnorm[(li*4 + l2)*32 + c2];
    const float bb = bnorm[(li*4 + l2)*32 + c2];
    const float sg = fmaxf(gg*nrm + bb, 0.f);
    facsh[c2*4 + l2] = sg / nrm;
  }
  __syncthreads();
  const float g0 = acc0 * facsh[oc*4 + l0];
  const float g1 = acc1 * facsh[oc*4 + l1];
  *reinterpret_cast<float2*>(fnext + (size_t)bd * 512 + slot0) = make_float2(g0, g1);

  if (nf_out) {                        // fused nodefeats for the NEXT layer
    osh[slot0] = g0; osh[slot0 + 1] = g1;
    __syncthreads();
    nf_project(osh, nf_out + (size_t)bd * 1792, Wk, Wv, Wq, li + 1, tid);
  }
}

// ---------------- readout: invariant norms -> mean over nodes -> Wfinal ----------------
__global__ __launch_bounds__(256) void readout_k(const float* __restrict__ f,
    const float* __restrict__ Wfinal, const float* __restrict__ bfinal,
    float* __restrict__ out) {
  __shared__ float invs[2][128];
  __shared__ float inv1[128];
  const int b = blockIdx.x;
  const int tid = threadIdx.x;
  const int j = tid & 127, half = tid >> 7;
  float p = 0.f;
  for (int n = half*32; n < half*32 + 32; n++) {
    const float* fn = f + (size_t)(b*64 + n) * 512;
    float v;
    if (j < 32) {
      v = fn[j*16];
    } else {
      int l = j >> 5, c = j & 31;
      int mb = mgb_of(l), M = 2*l + 1;
      float ss = 0.f;
      for (int m = 0; m < M; m++) { float t = fn[c*16 + mb + m]; ss += t*t; }
      v = sqrtf(ss + 1e-6f);
    }
    p += v;
  }
  invs[half][j] = p;
  __syncthreads();
  if (tid < 128) inv1[tid] = (invs[0][tid] + invs[1][tid]) * (1.0f / 64.0f);
  __syncthreads();
  if (tid < 128) {
    float acc = bfinal[tid];
    for (int k = 0; k < 128; k++) acc += inv1[k] * Wfinal[k*128 + tid];
    out[b*128 + tid] = acc;
  }
}

extern "C" void kernel_launch(void* const* d_in, const int* in_sizes, int n_in,
                              void* d_out, int out_size, void* d_ws, size_t ws_size,
                              hipStream_t stream) {
  (void)in_sizes; (void)n_in; (void)out_size; (void)ws_size;
  const float* h      = (const float*)d_in[0];
  const float* x      = (const float*)d_in[1];
  const int*   bond   = (const int*)d_in[2];
  const float* Wemb   = (const float*)d_in[3];
  const float* rw1    = (const float*)d_in[4];
  const float* rb1    = (const float*)d_in[5];
  const float* rw2    = (const float*)d_in[6];
  const float* rb2    = (const float*)d_in[7];
  const float* Wk     = (const float*)d_in[8];
  const float* Wv     = (const float*)d_in[9];
  const float* Wq     = (const float*)d_in[10];
  const float* Wself  = (const float*)d_in[11];
  const float* gnorm  = (const float*)d_in[12];
  const float* bnorm  = (const float*)d_in[13];
  const float* Wfinal = (const float*)d_in[14];
  const float* bfinal = (const float*)d_in[15];
  float* out = (float*)d_out;

  float* ws  = (float*)d_ws;
  float* fA  = ws;                       // 524288 floats
  float* fB  = ws + 524288;              // 524288 floats
  float* nfA = ws + 2 * 524288;          // 1835008 floats
  float* nfB = nfA + 1835008;            // 1835008 floats

  prep_k<<<1024, 256, 0, stream>>>(h, Wemb, Wk, Wv, Wq, fA, nfA);

  float* fc = fA;  float* fn2 = fB;
  float* nfc = nfA; float* nfn = nfB;
  for (int li = 0; li < 4; li++) {
    attn_k<<<1024, 256, 0, stream>>>(fc, nfc, fn2, x, bond,
                                     rw1, rb1, rw2, rb2, Wself, gnorm, bnorm,
                                     Wk, Wv, Wq,
                                     (li < 3) ? nfn : nullptr, li);
    float* t = fc; fc = fn2; fn2 = t;
    t = nfc; nfc = nfn; nfn = t;
  }

  readout_k<<<16, 256, 0, stream>>>(fc, Wfinal, bfinal, out);
}